// Round 18
// baseline (557.032 us; speedup 1.0000x reference)
//
#include <hip/hip_runtime.h>
#include <math.h>

// B=4, S=8192, D=768, W=3D=2304
// Three ws layouts, chosen by ws_size (deterministic):
//  T1 (231,282,688 B): tw | h0f | xb4 | w_inb | w_outb | x3Tb[4]
//  T2 (193,533,952 B): tw | h0f | xb  | w_inb | w_outb | x3Tb[4]
//  T3 (80.3 MB):       tw | h0f | xb  | w_inb | w_outb | x3Tb[1]
// h0T (fp32 transient) aliases the region right after h0f (consumed before it's written).
// fused_fft: 1024 threads, 128 KiB dynamic LDS, 2 d-rows per block;
// __launch_bounds__(1024, 4) pins 16 waves/CU so VGPR cap = 128 (no spill — R17 lesson).

typedef unsigned short u16;
typedef short s16x8 __attribute__((ext_vector_type(8)));
typedef float f32x4 __attribute__((ext_vector_type(4)));
typedef u16 u16x8 __attribute__((ext_vector_type(8)));

#define LPZ(i) ((i) ^ (((i) >> 4) & 15) ^ (((i) >> 8) & 15))
#define BREV13(k) ((int)(__brev((unsigned)(k)) >> 19))
#define BREV12(k) ((int)(__brev((unsigned)(k)) >> 20))
#define CMUL(rr, ri, xr, xi, wr, wi) { rr = (xr)*(wr) - (xi)*(wi); ri = (xr)*(wi) + (xi)*(wr); }

__device__ __forceinline__ u16 f2bf(float f) {
  unsigned u = __float_as_uint(f);
  u = (u + 0x7FFFu + ((u >> 16) & 1u)) >> 16;
  return (u16)u;
}
__device__ __forceinline__ float bf2f(u16 u) { return __uint_as_float(((unsigned)u) << 16); }

__device__ __forceinline__ void glds16(const void* g, void* l) {
  __builtin_amdgcn_global_load_lds((const __attribute__((address_space(1))) unsigned*)g,
                                   (__attribute__((address_space(3))) unsigned*)l, 16, 0, 0);
}

// ---------------------------------------------------------------- float -> bf16
__global__ __launch_bounds__(256) void cvt_bf16(const float* __restrict__ in,
                                                u16* __restrict__ out, int n8) {
  const int i = blockIdx.x * 256 + threadIdx.x;
  if (i < n8) {
    const float4 a = ((const float4*)in)[i * 2];
    const float4 b = ((const float4*)in)[i * 2 + 1];
    u16x8 r;
    r[0] = f2bf(a.x); r[1] = f2bf(a.y); r[2] = f2bf(a.z); r[3] = f2bf(a.w);
    r[4] = f2bf(b.x); r[5] = f2bf(b.y); r[6] = f2bf(b.z); r[7] = f2bf(b.w);
    ((u16x8*)out)[i] = r;
  }
}

// ---------------------------------------------------------------- MFMA GEMM (glds16 both operands)
template <int BIAS_M>
__global__ __launch_bounds__(256) void gemm_bt(const u16* __restrict__ A,
                                               const u16* __restrict__ B,
                                               const float* __restrict__ bias,
                                               void* __restrict__ Cout,
                                               int N, int K,
                                               size_t As_str, size_t Bs_str, size_t Cs_str) {
  __shared__ __align__(16) u16 As[4096];
  __shared__ __align__(16) u16 Bs[4096];
  A += (size_t)blockIdx.z * As_str;
  B += (size_t)blockIdx.z * Bs_str;
  const int tid = threadIdx.x;
  const int w = tid >> 6, l = tid & 63;
  const int m0 = blockIdx.y * 128, n0 = blockIdx.x * 128;
  const int wr = w >> 1, wc = w & 1;
  const int lr = l & 15, kc = l >> 4;

  const int p0 = w * 64 + l;
  const int p1 = p0 + 256;
  const int sl0 = (p0 & 7) ^ ((p0 >> 3) & 7);
  const int sl1 = (p1 & 7) ^ ((p1 >> 3) & 7);
  const int r0 = ((p0 >> 3) << 1) | (sl0 >> 2), ka = (sl0 & 3) << 3;
  const int r1 = ((p1 >> 3) << 1) | (sl1 >> 2), kb = (sl1 & 3) << 3;
  const u16* gA0 = A + (size_t)(m0 + r0) * K + ka;
  const u16* gA1 = A + (size_t)(m0 + r1) * K + kb;
  const u16* gB0 = B + (size_t)(n0 + r0) * K + ka;
  const u16* gB1 = B + (size_t)(n0 + r1) * K + kb;
  u16* lA0 = &As[(size_t)w * 512];
  u16* lA1 = &As[(size_t)(4 + w) * 512];
  u16* lB0 = &Bs[(size_t)w * 512];
  u16* lB1 = &Bs[(size_t)(4 + w) * 512];

  f32x4 acc[4][4] = {};

  for (int k0 = 0; k0 < K; k0 += 32) {
    glds16(gA0 + k0, lA0);
    glds16(gA1 + k0, lA1);
    glds16(gB0 + k0, lB0);
    glds16(gB1 + k0, lB1);
    __syncthreads();
    s16x8 af[4], bfr[4];
#pragma unroll
    for (int mi = 0; mi < 4; ++mi) {
      const int row = wr * 64 + mi * 16 + lr;
      const int slot = (((lr & 1) << 2) | kc) ^ ((lr >> 1) & 7);
      af[mi] = *(const s16x8*)&As[(row >> 1) * 64 + slot * 8];
    }
#pragma unroll
    for (int ni = 0; ni < 4; ++ni) {
      const int row = wc * 64 + ni * 16 + lr;
      const int slot = (((lr & 1) << 2) | kc) ^ ((lr >> 1) & 7);
      bfr[ni] = *(const s16x8*)&Bs[(row >> 1) * 64 + slot * 8];
    }
#pragma unroll
    for (int mi = 0; mi < 4; ++mi)
#pragma unroll
      for (int ni = 0; ni < 4; ++ni)
        acc[mi][ni] = __builtin_amdgcn_mfma_f32_16x16x32_bf16(af[mi], bfr[ni], acc[mi][ni], 0, 0, 0);
    __syncthreads();
  }

  const int rbase = m0 + wr * 64 + (kc << 2);
  const int cbase = n0 + wc * 64 + lr;
#pragma unroll
  for (int mi = 0; mi < 4; ++mi)
#pragma unroll
    for (int j = 0; j < 4; ++j) {
      const int row = rbase + mi * 16 + j;
      const float bm = BIAS_M ? bias[row] : 0.f;
#pragma unroll
      for (int ni = 0; ni < 4; ++ni) {
        const int col = cbase + ni * 16;
        const float v = acc[mi][ni][j] + (BIAS_M ? bm : bias[col]);
        if (BIAS_M) ((u16*)Cout)[(size_t)blockIdx.z * Cs_str + (size_t)row * N + col] = f2bf(v);
        else ((float*)Cout)[(size_t)blockIdx.z * Cs_str + (size_t)row * N + col] = v;
      }
    }
}

// ---------------------------------------------------------------- twiddles exp(-2pi i k/8192)
__global__ void twfill(float2* __restrict__ tw) {
  const int k = blockIdx.x * 256 + threadIdx.x;
  if (k < 8192) {
    const double t = -2.0 * 3.14159265358979323846 * (double)k / 8192.0;
    tw[k] = make_float2((float)cos(t), (float)sin(t));
  }
}

// ---------------------------------------------------------------- h0 (8192 x 768) -> h0T (768 x 8192) fp32
__global__ __launch_bounds__(256) void transp(const float* __restrict__ in, float* __restrict__ out) {
  __shared__ float T[64][65];
  const int d0 = blockIdx.x * 64, s0 = blockIdx.y * 64;
  const int c = threadIdx.x & 63, r0 = threadIdx.x >> 6;
#pragma unroll
  for (int i = 0; i < 16; ++i) {
    const int r = r0 + i * 4;
    T[r][c] = in[(size_t)(s0 + r) * 768 + d0 + c];
  }
  __syncthreads();
#pragma unroll
  for (int i = 0; i < 16; ++i) {
    const int r = r0 + i * 4;
    out[(size_t)(d0 + r) * 8192 + s0 + c] = T[c][r];
  }
}

// ---------------------------------------------------------------- butterfly bodies
__device__ __forceinline__ void dif4(float2& A, float2& B, float2& C, float2& D,
                                     float2 w1, float2 w2, float2 w3) {
  const float apr = A.x + C.x, api = A.y + C.y, amr = A.x - C.x, ami = A.y - C.y;
  const float bpr = B.x + D.x, bpi = B.y + D.y, bmr = B.x - D.x, bmi = B.y - D.y;
  const float2 o0 = make_float2(apr + bpr, api + bpi);
  const float x1r = apr - bpr, x1i = api - bpi;
  float2 o1; CMUL(o1.x, o1.y, x1r, x1i, w2.x, w2.y);
  const float x2r = amr + bmi, x2i = ami - bmr;
  float2 o2; CMUL(o2.x, o2.y, x2r, x2i, w1.x, w1.y);
  const float x3r = amr - bmi, x3i = ami + bmr;
  float2 o3; CMUL(o3.x, o3.y, x3r, x3i, w3.x, w3.y);
  A = o0; B = o1; C = o2; D = o3;
}

__device__ __forceinline__ void dit4(float2& A, float2& B, float2& C, float2& D,
                                     float2 w1, float2 w2) {
  float vbr, vbi, vdr, vdi;
  CMUL(vbr, vbi, B.x, B.y, w2.x, w2.y);
  CMUL(vdr, vdi, D.x, D.y, w2.x, w2.y);
  const float a1r = A.x + vbr, a1i = A.y + vbi;
  const float b1r = A.x - vbr, b1i = A.y - vbi;
  const float c1r = C.x + vdr, c1i = C.y + vdi;
  const float d1r = C.x - vdr, d1i = C.y - vdi;
  float t1r, t1i, ur, ui;
  CMUL(t1r, t1i, c1r, c1i, w1.x, w1.y);
  CMUL(ur, ui, d1r, d1i, w1.y, -w1.x);
  A = make_float2(a1r + t1r, a1i + t1i);
  C = make_float2(a1r - t1r, a1i - t1i);
  B = make_float2(b1r + ur,  b1i + ui);
  D = make_float2(b1r - ur,  b1i - ui);
}

// ---------------------------------------------------------------- radix-16 passes
__device__ __forceinline__ void fwd_pass16(float2* z, const float2* __restrict__ tw,
                                           int base, int jp, int st, int e) {
  float2 v[16]; int idx[16];
#pragma unroll
  for (int m = 0; m < 16; ++m) { idx[m] = LPZ(base + m * st); v[m] = z[idx[m]]; }
#pragma unroll
  for (int c = 0; c < 4; ++c) {
    const int jc = jp + c * st;
    dif4(v[c], v[c + 4], v[c + 8], v[c + 12],
         tw[jc << e], tw[(2 * jc) << e], tw[(3 * jc) << e]);
  }
  const float2 u1 = tw[jp << (e + 2)];
  const float2 u2 = tw[(2 * jp) << (e + 2)];
  const float2 u3 = tw[(3 * jp) << (e + 2)];
#pragma unroll
  for (int a = 0; a < 4; ++a)
    dif4(v[4 * a], v[4 * a + 1], v[4 * a + 2], v[4 * a + 3], u1, u2, u3);
#pragma unroll
  for (int m = 0; m < 16; ++m) z[idx[m]] = v[m];
}

__device__ __forceinline__ void inv_pass16(float2* z, const float2* __restrict__ tw,
                                           int base, int jp, int st, int e) {
  float2 v[16]; int idx[16];
#pragma unroll
  for (int m = 0; m < 16; ++m) { idx[m] = LPZ(base + m * st); v[m] = z[idx[m]]; }
  const float2 w1 = tw[jp << e];
  const float2 w2 = tw[(2 * jp) << e];
#pragma unroll
  for (int a = 0; a < 4; ++a)
    dit4(v[4 * a], v[4 * a + 1], v[4 * a + 2], v[4 * a + 3], w1, w2);
#pragma unroll
  for (int c = 0; c < 4; ++c) {
    const int jpp = c * st + jp;
    dit4(v[c], v[c + 4], v[c + 8], v[c + 12],
         tw[jpp << (e - 2)], tw[(2 * jpp) << (e - 2)]);
  }
#pragma unroll
  for (int m = 0; m < 16; ++m) z[idx[m]] = v[m];
}

// ---------------------------------------------------------------- forward 8192: 3 radix-16 + radix-2
template <int NT>
__device__ __forceinline__ void fwd8192(float2* z, const float2* __restrict__ tw, int tid) {
  fwd_pass16(z, tw, tid, tid, 512, 0);
  __syncthreads();
  fwd_pass16(z, tw, ((tid >> 5) << 9) | (tid & 31), tid & 31, 32, 4);
  __syncthreads();
  fwd_pass16(z, tw, ((tid >> 1) << 5) | (tid & 1), tid & 1, 2, 8);
  __syncthreads();
#pragma unroll
  for (int t = 0; t < 8; ++t) {
    const int g = tid + t * 512;
    const int p = LPZ(2 * g), q = LPZ(2 * g + 1);
    const float2 U = z[p], V = z[q];
    z[p] = make_float2(U.x + V.x, U.y + V.y);
    z[q] = make_float2(U.x - V.x, U.y - V.y);
  }
  __syncthreads();
}

// ---------------------------------------------------------------- inverse-core 4096: 3 radix-16
template <int NT>
__device__ __forceinline__ void inv4096(float2* z, const float2* __restrict__ tw, int tid) {
  if (tid < 256) inv_pass16(z, tw, tid << 4, 0, 1, 11);
  __syncthreads();
  if (tid < 256) inv_pass16(z, tw, ((tid >> 4) << 8) | (tid & 15), tid & 15, 16, 7);
  __syncthreads();
  if (tid < 256) inv_pass16(z, tw, tid, tid, 256, 3);
  __syncthreads();
}

// ---------------------------------------------------------------- paired h0 FFT
__global__ __launch_bounds__(512, 2) void fft_h0_pair(const float* __restrict__ h0T,
                                                      const float2* __restrict__ tw,
                                                      float2* __restrict__ h0f) {
  __shared__ float2 z[8192];
  const int d0 = blockIdx.x * 2, tid = threadIdx.x;
  const float* srcA = h0T + (size_t)d0 * 8192;
  const float* srcB = srcA + 8192;
  const int s0 = tid << 4;
#pragma unroll
  for (int m = 0; m < 16; ++m) z[LPZ(s0 + m)] = make_float2(srcA[s0 + m], srcB[s0 + m]);
  __syncthreads();
  fwd8192<512>(z, tw, tid);
  float2* H0 = h0f + (size_t)d0 * 4097;
  float2* H1 = H0 + 4097;
  for (int k = tid; k <= 4096; k += 512) {
    const float2 Zk = z[LPZ(BREV13(k))];
    const float2 Zm = z[LPZ(BREV13((8192 - k) & 8191))];
    H0[k] = make_float2(0.5f * (Zk.x + Zm.x), 0.5f * (Zk.y - Zm.y));
    H1[k] = make_float2(0.5f * (Zk.y + Zm.y), 0.5f * (Zm.x - Zk.x));
  }
}

// ---------------------------------------------------------------- fused per-(b,d) row pipeline
// 1024 threads, 128 KiB dynamic LDS: half h = tid>>9 processes row d = 2*blockIdx.x + h.
// __launch_bounds__(1024, 4): 16 waves/CU -> VGPR cap 128, no spill.
__global__ __launch_bounds__(1024, 4) void fused_fft(u16* __restrict__ x3T,
                                                     const float2* __restrict__ tw,
                                                     const float2* __restrict__ h0f,
                                                     const float* __restrict__ w_short,
                                                     const float* __restrict__ b_short,
                                                     const float* __restrict__ w_cond1,
                                                     const float* __restrict__ b_cond1,
                                                     const float* __restrict__ w_cond2,
                                                     const float* __restrict__ b_cond2,
                                                     size_t bstr) {
  extern __shared__ __align__(16) float2 zall[];
  const int half = threadIdx.x >> 9;
  const int t = threadIdx.x & 511;
  float2* z = zall + (size_t)half * 8192;
  const int d = blockIdx.x * 2 + half;
  x3T += (size_t)blockIdx.y * bstr;
  u16* g0 = x3T + (size_t)d * 8192;
  const u16* g1 = x3T + (size_t)(768 + d) * 8192;
  const u16* g2 = x3T + (size_t)(1536 + d) * 8192;

  const float q0 = w_cond1[d * 3], q1 = w_cond1[d * 3 + 1], q2 = w_cond1[d * 3 + 2], bc1 = b_cond1[d];
  const float t00 = w_short[d * 3], t01 = w_short[d * 3 + 1], t02 = w_short[d * 3 + 2], bs0 = b_short[d];
  const float t10 = w_short[(768 + d) * 3], t11 = w_short[(768 + d) * 3 + 1], t12 = w_short[(768 + d) * 3 + 2], bs1 = b_short[768 + d];
  const float t20 = w_short[(1536 + d) * 3], t21 = w_short[(1536 + d) * 3 + 1], t22 = w_short[(1536 + d) * 3 + 2], bs2 = b_short[1536 + d];

  const int s0 = t << 4;

  // conv phase (global -> regs -> z): z[s] = hc[s] + i*y[s]
  {
    const u16x8 ga0 = *(const u16x8*)&g0[s0];
    const u16x8 ga1 = *(const u16x8*)&g0[s0 + 8];
    const u16x8 gb0 = *(const u16x8*)&g2[s0];
    const u16x8 gb1 = *(const u16x8*)&g2[s0 + 8];
    float a[18], bz[18];
    a[0]  = s0 ? bf2f(g0[s0 - 1]) : 0.f;
    bz[0] = s0 ? bf2f(g2[s0 - 1]) : 0.f;
#pragma unroll
    for (int m = 0; m < 8; ++m) {
      a[1 + m] = bf2f(ga0[m]);  a[9 + m] = bf2f(ga1[m]);
      bz[1 + m] = bf2f(gb0[m]); bz[9 + m] = bf2f(gb1[m]);
    }
    a[17]  = (s0 + 16 < 8192) ? bf2f(g0[s0 + 16]) : 0.f;
    bz[17] = (s0 + 16 < 8192) ? bf2f(g2[s0 + 16]) : 0.f;
#pragma unroll
    for (int m = 0; m < 16; ++m) {
      const float s1v = t00 * a[m] + t01 * a[m + 1] + t02 * a[m + 2] + bs0;
      const float vvv = t20 * bz[m] + t21 * bz[m + 1] + t22 * bz[m + 2] + bs2;
      const float hcv = q0 * bz[m] + q1 * bz[m + 1] + q2 * bz[m + 2] + bc1;
      z[LPZ(s0 + m)] = make_float2(hcv, s1v * vvv);
    }
  }
  __syncthreads();

  fwd8192<512>(z, tw, t);

  // two-for-one unpack
  float hm[9], yr[9], yi[9];
#pragma unroll
  for (int j = 0; j < 9; ++j) {
    const int k = t + j * 512;
    if (k <= 4096) {
      const float2 Zk = z[LPZ(BREV13(k))];
      const float2 Zm = z[LPZ(BREV13((8192 - k) & 8191))];
      const float hcr = 0.5f * (Zk.x + Zm.x), hci = 0.5f * (Zk.y - Zm.y);
      hm[j] = sqrtf(hcr * hcr + hci * hci);
      yr[j] = 0.5f * (Zk.y + Zm.y);
      yi[j] = 0.5f * (Zm.x - Zk.x);
    }
  }
  __syncthreads();
  float* hbuf = (float*)z;
#pragma unroll
  for (int j = 0; j < 9; ++j) { const int k = t + j * 512; if (k <= 4096) hbuf[k] = hm[j]; }
  __syncthreads();

  // h_adapt + G = Y * (h0f + ha)
  const float c0 = w_cond2[d * 3], c1 = w_cond2[d * 3 + 1], c2 = w_cond2[d * 3 + 2], bb2 = b_cond2[d];
  const float2* H0 = h0f + (size_t)d * 4097;
  float gr[9], gi[9];
#pragma unroll
  for (int j = 0; j < 9; ++j) {
    const int k = t + j * 512;
    if (k <= 4096) {
      const float a = k ? hbuf[k - 1] : 0.f;
      const float m = hbuf[k];
      const float zn = (k < 4096) ? hbuf[k + 1] : 0.f;
      const float ha = c0 * a + c1 * m + c2 * zn + bb2;
      const float2 h = H0[k];
      const float hr = h.x + ha, hi = h.y;
      gr[j] = yr[j] * hr - yi[j] * hi;
      gi[j] = yr[j] * hi + yi[j] * hr;
      if (k == 0 || k == 4096) gi[j] = 0.f;
    }
  }
  __syncthreads();
#pragma unroll
  for (int j = 0; j < 9; ++j) {
    const int k = t + j * 512;
    if (k <= 4096) z[LPZ(k)] = make_float2(gr[j], gi[j]);
  }
  __syncthreads();

  // half-size packing, store conj(Zc) bit-reversed
  float zr2[8], zi2[8];
#pragma unroll
  for (int j = 0; j < 8; ++j) {
    const int kc = t + j * 512;
    const float2 Ga = z[LPZ(kc)];
    const float2 Gb = z[LPZ(4096 - kc)];
    const float Er = 0.5f * (Ga.x + Gb.x), Ei = 0.5f * (Ga.y - Gb.y);
    const float Pr = 0.5f * (Ga.x - Gb.x), Pi = 0.5f * (Ga.y + Gb.y);
    const float2 w = tw[kc];
    const float Or = Pr * w.x + Pi * w.y;
    const float Oi = Pi * w.x - Pr * w.y;
    zr2[j] = Er - Oi;
    zi2[j] = -(Ei + Or);
  }
  __syncthreads();
#pragma unroll
  for (int j = 0; j < 8; ++j) {
    const int kc = t + j * 512;
    z[LPZ(BREV12(kc))] = make_float2(zr2[j], zi2[j]);
  }
  __syncthreads();

  // T14: issue g1 loads now; HBM latency hides under inv4096
  const u16x8 g1a = *(const u16x8*)&g1[s0];
  const u16x8 g1b = *(const u16x8*)&g1[s0 + 8];
  const float ge0 = s0 ? bf2f(g1[s0 - 1]) : 0.f;
  const float ge1 = (s0 + 16 < 8192) ? bf2f(g1[s0 + 16]) : 0.f;

  inv4096<512>(z, tw, t);

  // final: y2 = irfft * conv3(g1,ws1) -> g0 (bf16)
  {
    float gg[18];
    gg[0] = ge0;
#pragma unroll
    for (int m = 0; m < 8; ++m) { gg[1 + m] = bf2f(g1a[m]); gg[9 + m] = bf2f(g1b[m]); }
    gg[17] = ge1;
    float2 zv[8];
#pragma unroll
    for (int r = 0; r < 8; ++r) zv[r] = z[LPZ((s0 >> 1) + r)];
    const float invM = 1.0f / 4096.0f;
    u16x8 o0, o1;
#pragma unroll
    for (int m = 0; m < 16; ++m) {
      const float xs = ((m & 1) ? -zv[m >> 1].y : zv[m >> 1].x) * invM;
      const float s2v = t10 * gg[m] + t11 * gg[m + 1] + t12 * gg[m + 2] + bs1;
      const u16 val = f2bf(xs * s2v);
      if (m < 8) o0[m] = val; else o1[m - 8] = val;
    }
    *(u16x8*)&g0[s0] = o0;
    *(u16x8*)&g0[s0 + 8] = o1;
  }
}

// ---------------------------------------------------------------- y2 transpose, vectorized u16x8 both sides
__global__ __launch_bounds__(256) void y2tv(const u16* __restrict__ Yr, u16* __restrict__ y2b,
                                            size_t in_str, size_t out_str) {
  __shared__ __align__(16) u16 T[4096];
  Yr  += (size_t)blockIdx.z * in_str;
  y2b += (size_t)blockIdx.z * out_str;
  const int d0 = blockIdx.x * 64, s0 = blockIdx.y * 64;
  const int t = threadIdx.x;
  const int r = t >> 2;
  const int c0 = t & 3;
#pragma unroll
  for (int h = 0; h < 2; ++h) {
    const int cc = c0 + h * 4;
    const u16x8 v = *(const u16x8*)&Yr[(size_t)(d0 + r) * 8192 + s0 + cc * 8];
#pragma unroll
    for (int q = 0; q < 8; ++q) {
      const int s = cc * 8 + q;
      T[s * 64 + (((r >> 3) ^ (s & 7)) << 3) + (r & 7)] = v[q];
    }
  }
  __syncthreads();
  const int l = t & 63, w = t >> 6;
#pragma unroll
  for (int h = 0; h < 2; ++h) {
    const int s = (w + h * 4) * 8 + (l >> 3);
    const int j = l & 7;
    const u16x8 o = *(const u16x8*)&T[s * 64 + ((j ^ (s & 7)) << 3)];
    *(u16x8*)&y2b[(size_t)(s0 + s) * 768 + d0 + j * 8] = o;
  }
}

// ---------------------------------------------------------------- launch
extern "C" void kernel_launch(void* const* d_in, const int* in_sizes, int n_in,
                              void* d_out, int out_size, void* d_ws, size_t ws_size,
                              hipStream_t stream) {
  (void)in_sizes; (void)n_in; (void)out_size;
  const float* x       = (const float*)d_in[0];
  const float* w_in    = (const float*)d_in[1];
  const float* b_in    = (const float*)d_in[2];
  const float* w_short = (const float*)d_in[3];
  const float* b_short = (const float*)d_in[4];
  const float* w_cond1 = (const float*)d_in[5];
  const float* b_cond1 = (const float*)d_in[6];
  const float* w_cond2 = (const float*)d_in[7];
  const float* b_cond2 = (const float*)d_in[8];
  const float* h0      = (const float*)d_in[9];
  const float* w_out   = (const float*)d_in[10];
  const float* b_out   = (const float*)d_in[11];

  float* ws = (float*)d_ws;
  float2* tw  = (float2*)ws;                      // [0, 16384)
  float2* h0f = (float2*)(ws + 16384);            // [16384, 6309376)
  float*  h0T = ws + 6309376;                     // transient (24 MB), consumed early
  const size_t BSTR = 18874368ull;                // u16 per x3T batch
  const size_t XSTR = 6291456ull;                 // u16 per x batch
  const size_t FFT_LDS = 131072;                  // 128 KiB dynamic LDS

  const bool t1 = ws_size >= 231282688ull;
  const bool t2 = !t1 && ws_size >= 193533952ull;

  twfill<<<32, 256, 0, stream>>>(tw);
  transp<<<dim3(12, 128), 256, 0, stream>>>(h0, h0T);
  fft_h0_pair<<<384, 512, 0, stream>>>(h0T, tw, h0f);

  if (t1) {
    u16* xb4    = (u16*)(ws + 6309376);
    u16* w_inb  = (u16*)(ws + 18892288);
    u16* w_outb = (u16*)(ws + 19777024);
    u16* x3Tb4  = (u16*)(ws + 20071936);
    cvt_bf16<<<864, 256, 0, stream>>>(w_in, w_inb, 221184);
    cvt_bf16<<<288, 256, 0, stream>>>(w_out, w_outb, 73728);
    cvt_bf16<<<12288, 256, 0, stream>>>(x, xb4, 3145728);
    gemm_bt<1><<<dim3(64, 18, 4), 256, 0, stream>>>(w_inb, xb4, b_in, x3Tb4,
                                                    8192, 768, 0, XSTR, BSTR);
    fused_fft<<<dim3(384, 4), 1024, FFT_LDS, stream>>>(x3Tb4, tw, h0f,
                                                       w_short, b_short, w_cond1, b_cond1,
                                                       w_cond2, b_cond2, BSTR);
    y2tv<<<dim3(12, 128, 4), 256, 0, stream>>>(x3Tb4, x3Tb4 + XSTR, BSTR, BSTR);
    gemm_bt<0><<<dim3(6, 64, 4), 256, 0, stream>>>(x3Tb4 + XSTR, w_outb, b_out,
                                                   (float*)d_out, 768, 768,
                                                   BSTR, 0, XSTR);
  } else if (t2) {
    u16* xb     = (u16*)(ws + 6309376);
    u16* w_inb  = (u16*)(ws + 9455104);
    u16* w_outb = (u16*)(ws + 10339840);
    u16* x3Tb   = (u16*)(ws + 10634752);
    cvt_bf16<<<864, 256, 0, stream>>>(w_in, w_inb, 221184);
    cvt_bf16<<<288, 256, 0, stream>>>(w_out, w_outb, 73728);
    for (int b = 0; b < 4; ++b) {
      cvt_bf16<<<3072, 256, 0, stream>>>(x + (size_t)b * XSTR, xb, 786432);
      gemm_bt<1><<<dim3(64, 18), 256, 0, stream>>>(w_inb, xb, b_in,
                                                   x3Tb + (size_t)b * BSTR, 8192, 768, 0, 0, 0);
    }
    fused_fft<<<dim3(384, 4), 1024, FFT_LDS, stream>>>(x3Tb, tw, h0f,
                                                       w_short, b_short, w_cond1, b_cond1,
                                                       w_cond2, b_cond2, BSTR);
    y2tv<<<dim3(12, 128, 4), 256, 0, stream>>>(x3Tb, x3Tb + XSTR, BSTR, BSTR);
    gemm_bt<0><<<dim3(6, 64, 4), 256, 0, stream>>>(x3Tb + XSTR, w_outb, b_out,
                                                   (float*)d_out, 768, 768,
                                                   BSTR, 0, XSTR);
  } else {
    u16* xb     = (u16*)(ws + 6309376);
    u16* w_inb  = (u16*)(ws + 9455104);
    u16* w_outb = (u16*)(ws + 10339840);
    u16* x3Tb   = (u16*)(ws + 10634752);
    cvt_bf16<<<864, 256, 0, stream>>>(w_in, w_inb, 221184);
    cvt_bf16<<<288, 256, 0, stream>>>(w_out, w_outb, 73728);
    for (int b = 0; b < 4; ++b) {
      cvt_bf16<<<3072, 256, 0, stream>>>(x + (size_t)b * XSTR, xb, 786432);
      gemm_bt<1><<<dim3(64, 18), 256, 0, stream>>>(w_inb, xb, b_in, x3Tb, 8192, 768, 0, 0, 0);
      fused_fft<<<dim3(384, 1), 1024, FFT_LDS, stream>>>(x3Tb, tw, h0f,
                                                         w_short, b_short, w_cond1, b_cond1,
                                                         w_cond2, b_cond2, 0);
      y2tv<<<dim3(12, 128, 1), 256, 0, stream>>>(x3Tb, x3Tb + XSTR, 0, 0);
      gemm_bt<0><<<dim3(6, 64, 1), 256, 0, stream>>>(x3Tb + XSTR, w_outb, b_out,
                                                     (float*)d_out + (size_t)b * XSTR,
                                                     768, 768, 0, 0, 0);
    }
  }
}

// Round 19
// 524.171 us; speedup vs baseline: 1.0627x; 1.0627x over previous
//
#include <hip/hip_runtime.h>
#include <math.h>

// B=4, S=8192, D=768, W=3D=2304
// Three ws layouts by ws_size: T1 231.3MB | T2 193.5MB | T3 80.3MB (see R15).
// fused_fft: back to 512 thr / static 64 KiB (R16 shell) + fwd tail fusion (stages 5,3,1
// in one register pass: 4 -> 3 LDS round-trips per forward FFT).

typedef unsigned short u16;
typedef short s16x8 __attribute__((ext_vector_type(8)));
typedef float f32x4 __attribute__((ext_vector_type(4)));
typedef u16 u16x8 __attribute__((ext_vector_type(8)));

#define LPZ(i) ((i) ^ (((i) >> 4) & 15) ^ (((i) >> 8) & 15))
#define BREV13(k) ((int)(__brev((unsigned)(k)) >> 19))
#define BREV12(k) ((int)(__brev((unsigned)(k)) >> 20))
#define CMUL(rr, ri, xr, xi, wr, wi) { rr = (xr)*(wr) - (xi)*(wi); ri = (xr)*(wi) + (xi)*(wr); }

__device__ __forceinline__ u16 f2bf(float f) {
  unsigned u = __float_as_uint(f);
  u = (u + 0x7FFFu + ((u >> 16) & 1u)) >> 16;
  return (u16)u;
}
__device__ __forceinline__ float bf2f(u16 u) { return __uint_as_float(((unsigned)u) << 16); }

__device__ __forceinline__ void glds16(const void* g, void* l) {
  __builtin_amdgcn_global_load_lds((const __attribute__((address_space(1))) unsigned*)g,
                                   (__attribute__((address_space(3))) unsigned*)l, 16, 0, 0);
}

// ---------------------------------------------------------------- float -> bf16
__global__ __launch_bounds__(256) void cvt_bf16(const float* __restrict__ in,
                                                u16* __restrict__ out, int n8) {
  const int i = blockIdx.x * 256 + threadIdx.x;
  if (i < n8) {
    const float4 a = ((const float4*)in)[i * 2];
    const float4 b = ((const float4*)in)[i * 2 + 1];
    u16x8 r;
    r[0] = f2bf(a.x); r[1] = f2bf(a.y); r[2] = f2bf(a.z); r[3] = f2bf(a.w);
    r[4] = f2bf(b.x); r[5] = f2bf(b.y); r[6] = f2bf(b.z); r[7] = f2bf(b.w);
    ((u16x8*)out)[i] = r;
  }
}

// ---------------------------------------------------------------- MFMA GEMM (glds16 both operands)
template <int BIAS_M>
__global__ __launch_bounds__(256) void gemm_bt(const u16* __restrict__ A,
                                               const u16* __restrict__ B,
                                               const float* __restrict__ bias,
                                               void* __restrict__ Cout,
                                               int N, int K,
                                               size_t As_str, size_t Bs_str, size_t Cs_str) {
  __shared__ __align__(16) u16 As[4096];
  __shared__ __align__(16) u16 Bs[4096];
  A += (size_t)blockIdx.z * As_str;
  B += (size_t)blockIdx.z * Bs_str;
  const int tid = threadIdx.x;
  const int w = tid >> 6, l = tid & 63;
  const int m0 = blockIdx.y * 128, n0 = blockIdx.x * 128;
  const int wr = w >> 1, wc = w & 1;
  const int lr = l & 15, kc = l >> 4;

  const int p0 = w * 64 + l;
  const int p1 = p0 + 256;
  const int sl0 = (p0 & 7) ^ ((p0 >> 3) & 7);
  const int sl1 = (p1 & 7) ^ ((p1 >> 3) & 7);
  const int r0 = ((p0 >> 3) << 1) | (sl0 >> 2), ka = (sl0 & 3) << 3;
  const int r1 = ((p1 >> 3) << 1) | (sl1 >> 2), kb = (sl1 & 3) << 3;
  const u16* gA0 = A + (size_t)(m0 + r0) * K + ka;
  const u16* gA1 = A + (size_t)(m0 + r1) * K + kb;
  const u16* gB0 = B + (size_t)(n0 + r0) * K + ka;
  const u16* gB1 = B + (size_t)(n0 + r1) * K + kb;
  u16* lA0 = &As[(size_t)w * 512];
  u16* lA1 = &As[(size_t)(4 + w) * 512];
  u16* lB0 = &Bs[(size_t)w * 512];
  u16* lB1 = &Bs[(size_t)(4 + w) * 512];

  f32x4 acc[4][4] = {};

  for (int k0 = 0; k0 < K; k0 += 32) {
    glds16(gA0 + k0, lA0);
    glds16(gA1 + k0, lA1);
    glds16(gB0 + k0, lB0);
    glds16(gB1 + k0, lB1);
    __syncthreads();
    s16x8 af[4], bfr[4];
#pragma unroll
    for (int mi = 0; mi < 4; ++mi) {
      const int row = wr * 64 + mi * 16 + lr;
      const int slot = (((lr & 1) << 2) | kc) ^ ((lr >> 1) & 7);
      af[mi] = *(const s16x8*)&As[(row >> 1) * 64 + slot * 8];
    }
#pragma unroll
    for (int ni = 0; ni < 4; ++ni) {
      const int row = wc * 64 + ni * 16 + lr;
      const int slot = (((lr & 1) << 2) | kc) ^ ((lr >> 1) & 7);
      bfr[ni] = *(const s16x8*)&Bs[(row >> 1) * 64 + slot * 8];
    }
#pragma unroll
    for (int mi = 0; mi < 4; ++mi)
#pragma unroll
      for (int ni = 0; ni < 4; ++ni)
        acc[mi][ni] = __builtin_amdgcn_mfma_f32_16x16x32_bf16(af[mi], bfr[ni], acc[mi][ni], 0, 0, 0);
    __syncthreads();
  }

  const int rbase = m0 + wr * 64 + (kc << 2);
  const int cbase = n0 + wc * 64 + lr;
#pragma unroll
  for (int mi = 0; mi < 4; ++mi)
#pragma unroll
    for (int j = 0; j < 4; ++j) {
      const int row = rbase + mi * 16 + j;
      const float bm = BIAS_M ? bias[row] : 0.f;
#pragma unroll
      for (int ni = 0; ni < 4; ++ni) {
        const int col = cbase + ni * 16;
        const float v = acc[mi][ni][j] + (BIAS_M ? bm : bias[col]);
        if (BIAS_M) ((u16*)Cout)[(size_t)blockIdx.z * Cs_str + (size_t)row * N + col] = f2bf(v);
        else ((float*)Cout)[(size_t)blockIdx.z * Cs_str + (size_t)row * N + col] = v;
      }
    }
}

// ---------------------------------------------------------------- twiddles exp(-2pi i k/8192)
__global__ void twfill(float2* __restrict__ tw) {
  const int k = blockIdx.x * 256 + threadIdx.x;
  if (k < 8192) {
    const double t = -2.0 * 3.14159265358979323846 * (double)k / 8192.0;
    tw[k] = make_float2((float)cos(t), (float)sin(t));
  }
}

// ---------------------------------------------------------------- h0 (8192 x 768) -> h0T (768 x 8192) fp32
__global__ __launch_bounds__(256) void transp(const float* __restrict__ in, float* __restrict__ out) {
  __shared__ float T[64][65];
  const int d0 = blockIdx.x * 64, s0 = blockIdx.y * 64;
  const int c = threadIdx.x & 63, r0 = threadIdx.x >> 6;
#pragma unroll
  for (int i = 0; i < 16; ++i) {
    const int r = r0 + i * 4;
    T[r][c] = in[(size_t)(s0 + r) * 768 + d0 + c];
  }
  __syncthreads();
#pragma unroll
  for (int i = 0; i < 16; ++i) {
    const int r = r0 + i * 4;
    out[(size_t)(d0 + r) * 8192 + s0 + c] = T[c][r];
  }
}

// ---------------------------------------------------------------- butterfly bodies
__device__ __forceinline__ void dif4(float2& A, float2& B, float2& C, float2& D,
                                     float2 w1, float2 w2, float2 w3) {
  const float apr = A.x + C.x, api = A.y + C.y, amr = A.x - C.x, ami = A.y - C.y;
  const float bpr = B.x + D.x, bpi = B.y + D.y, bmr = B.x - D.x, bmi = B.y - D.y;
  const float2 o0 = make_float2(apr + bpr, api + bpi);
  const float x1r = apr - bpr, x1i = api - bpi;
  float2 o1; CMUL(o1.x, o1.y, x1r, x1i, w2.x, w2.y);
  const float x2r = amr + bmi, x2i = ami - bmr;
  float2 o2; CMUL(o2.x, o2.y, x2r, x2i, w1.x, w1.y);
  const float x3r = amr - bmi, x3i = ami + bmr;
  float2 o3; CMUL(o3.x, o3.y, x3r, x3i, w3.x, w3.y);
  A = o0; B = o1; C = o2; D = o3;
}

__device__ __forceinline__ void dit4(float2& A, float2& B, float2& C, float2& D,
                                     float2 w1, float2 w2) {
  float vbr, vbi, vdr, vdi;
  CMUL(vbr, vbi, B.x, B.y, w2.x, w2.y);
  CMUL(vdr, vdi, D.x, D.y, w2.x, w2.y);
  const float a1r = A.x + vbr, a1i = A.y + vbi;
  const float b1r = A.x - vbr, b1i = A.y - vbi;
  const float c1r = C.x + vdr, c1i = C.y + vdi;
  const float d1r = C.x - vdr, d1i = C.y - vdi;
  float t1r, t1i, ur, ui;
  CMUL(t1r, t1i, c1r, c1i, w1.x, w1.y);
  CMUL(ur, ui, d1r, d1i, w1.y, -w1.x);
  A = make_float2(a1r + t1r, a1i + t1i);
  C = make_float2(a1r - t1r, a1i - t1i);
  B = make_float2(b1r + ur,  b1i + ui);
  D = make_float2(b1r - ur,  b1i - ui);
}

// ---------------------------------------------------------------- radix-16 passes
__device__ __forceinline__ void fwd_pass16(float2* z, const float2* __restrict__ tw,
                                           int base, int jp, int st, int e) {
  float2 v[16]; int idx[16];
#pragma unroll
  for (int m = 0; m < 16; ++m) { idx[m] = LPZ(base + m * st); v[m] = z[idx[m]]; }
#pragma unroll
  for (int c = 0; c < 4; ++c) {
    const int jc = jp + c * st;
    dif4(v[c], v[c + 4], v[c + 8], v[c + 12],
         tw[jc << e], tw[(2 * jc) << e], tw[(3 * jc) << e]);
  }
  const float2 u1 = tw[jp << (e + 2)];
  const float2 u2 = tw[(2 * jp) << (e + 2)];
  const float2 u3 = tw[(3 * jp) << (e + 2)];
#pragma unroll
  for (int a = 0; a < 4; ++a)
    dif4(v[4 * a], v[4 * a + 1], v[4 * a + 2], v[4 * a + 3], u1, u2, u3);
#pragma unroll
  for (int m = 0; m < 16; ++m) z[idx[m]] = v[m];
}

__device__ __forceinline__ void inv_pass16(float2* z, const float2* __restrict__ tw,
                                           int base, int jp, int st, int e) {
  float2 v[16]; int idx[16];
#pragma unroll
  for (int m = 0; m < 16; ++m) { idx[m] = LPZ(base + m * st); v[m] = z[idx[m]]; }
  const float2 w1 = tw[jp << e];
  const float2 w2 = tw[(2 * jp) << e];
#pragma unroll
  for (int a = 0; a < 4; ++a)
    dit4(v[4 * a], v[4 * a + 1], v[4 * a + 2], v[4 * a + 3], w1, w2);
#pragma unroll
  for (int c = 0; c < 4; ++c) {
    const int jpp = c * st + jp;
    dit4(v[c], v[c + 4], v[c + 8], v[c + 12],
         tw[jpp << (e - 2)], tw[(2 * jpp) << (e - 2)]);
  }
#pragma unroll
  for (int m = 0; m < 16; ++m) z[idx[m]] = v[m];
}

// ---------------------------------------------------------------- forward 8192: 2 radix-16 + fused {5,3,1} tail
// Tail: stages 5,3,1 act within 32-contiguous-element blocks -> 256 threads x 32 float2
// in registers, one LDS round-trip. Output layout = 13-bit bit-reversal (same network).
template <int NT>
__device__ __forceinline__ void fwd8192(float2* z, const float2* __restrict__ tw, int tid) {
  fwd_pass16(z, tw, tid, tid, 512, 0);                                  // stages 13,11
  __syncthreads();
  fwd_pass16(z, tw, ((tid >> 5) << 9) | (tid & 31), tid & 31, 32, 4);   // stages 9,7
  __syncthreads();
  if (tid < 256) {                                                      // stages 5,3,1
    float2 v[32];
#pragma unroll
    for (int n = 0; n < 32; ++n) v[n] = z[LPZ(tid * 32 + n)];
    // stage 5 (arm stride 8): p = parity + 2c enumerates 0..7, twiddle exp 8
#pragma unroll
    for (int p = 0; p < 8; ++p)
      dif4(v[p], v[p + 8], v[p + 16], v[p + 24],
           tw[p << 8], tw[(2 * p) << 8], tw[(3 * p) << 8]);
    // stage 3 (arm stride 2): even parity twiddle=1; odd parity tw[1024],tw[2048],tw[3072]
    const float2 one = make_float2(1.f, 0.f);
    const float2 o1 = tw[1 << 10], o2 = tw[2 << 10], o3 = tw[3 << 10];
#pragma unroll
    for (int a = 0; a < 4; ++a) {
      dif4(v[8 * a], v[8 * a + 2], v[8 * a + 4], v[8 * a + 6], one, one, one);
      dif4(v[8 * a + 1], v[8 * a + 3], v[8 * a + 5], v[8 * a + 7], o1, o2, o3);
    }
    // stage 1 (radix-2, adjacent pairs)
#pragma unroll
    for (int i = 0; i < 16; ++i) {
      const float2 U = v[2 * i], V = v[2 * i + 1];
      v[2 * i]     = make_float2(U.x + V.x, U.y + V.y);
      v[2 * i + 1] = make_float2(U.x - V.x, U.y - V.y);
    }
#pragma unroll
    for (int n = 0; n < 32; ++n) z[LPZ(tid * 32 + n)] = v[n];
  }
  __syncthreads();
}

// ---------------------------------------------------------------- inverse-core 4096: 3 radix-16
template <int NT>
__device__ __forceinline__ void inv4096(float2* z, const float2* __restrict__ tw, int tid) {
  if (tid < 256) inv_pass16(z, tw, tid << 4, 0, 1, 11);
  __syncthreads();
  if (tid < 256) inv_pass16(z, tw, ((tid >> 4) << 8) | (tid & 15), tid & 15, 16, 7);
  __syncthreads();
  if (tid < 256) inv_pass16(z, tw, tid, tid, 256, 3);
  __syncthreads();
}

// ---------------------------------------------------------------- paired h0 FFT
__global__ __launch_bounds__(512, 2) void fft_h0_pair(const float* __restrict__ h0T,
                                                      const float2* __restrict__ tw,
                                                      float2* __restrict__ h0f) {
  __shared__ float2 z[8192];
  const int d0 = blockIdx.x * 2, tid = threadIdx.x;
  const float* srcA = h0T + (size_t)d0 * 8192;
  const float* srcB = srcA + 8192;
  const int s0 = tid << 4;
#pragma unroll
  for (int m = 0; m < 16; ++m) z[LPZ(s0 + m)] = make_float2(srcA[s0 + m], srcB[s0 + m]);
  __syncthreads();
  fwd8192<512>(z, tw, tid);
  float2* H0 = h0f + (size_t)d0 * 4097;
  float2* H1 = H0 + 4097;
  for (int k = tid; k <= 4096; k += 512) {
    const float2 Zk = z[LPZ(BREV13(k))];
    const float2 Zm = z[LPZ(BREV13((8192 - k) & 8191))];
    H0[k] = make_float2(0.5f * (Zk.x + Zm.x), 0.5f * (Zk.y - Zm.y));
    H1[k] = make_float2(0.5f * (Zk.y + Zm.y), 0.5f * (Zm.x - Zk.x));
  }
}

// ---------------------------------------------------------------- fused per-(b,d) row pipeline (R16 shell)
__global__ __launch_bounds__(512, 2) void fused_fft(u16* __restrict__ x3T,
                                                    const float2* __restrict__ tw,
                                                    const float2* __restrict__ h0f,
                                                    const float* __restrict__ w_short,
                                                    const float* __restrict__ b_short,
                                                    const float* __restrict__ w_cond1,
                                                    const float* __restrict__ b_cond1,
                                                    const float* __restrict__ w_cond2,
                                                    const float* __restrict__ b_cond2,
                                                    size_t bstr) {
  __shared__ float2 z[8192];
  const int d = blockIdx.x, tid = threadIdx.x;
  x3T += (size_t)blockIdx.y * bstr;
  u16* g0 = x3T + (size_t)d * 8192;
  const u16* g1 = x3T + (size_t)(768 + d) * 8192;
  const u16* g2 = x3T + (size_t)(1536 + d) * 8192;

  const float q0 = w_cond1[d * 3], q1 = w_cond1[d * 3 + 1], q2 = w_cond1[d * 3 + 2], bc1 = b_cond1[d];
  const float t00 = w_short[d * 3], t01 = w_short[d * 3 + 1], t02 = w_short[d * 3 + 2], bs0 = b_short[d];
  const float t10 = w_short[(768 + d) * 3], t11 = w_short[(768 + d) * 3 + 1], t12 = w_short[(768 + d) * 3 + 2], bs1 = b_short[768 + d];
  const float t20 = w_short[(1536 + d) * 3], t21 = w_short[(1536 + d) * 3 + 1], t22 = w_short[(1536 + d) * 3 + 2], bs2 = b_short[1536 + d];

  const int s0 = tid << 4;

  // conv phase (global -> regs -> z): z[s] = hc[s] + i*y[s]
  {
    const u16x8 ga0 = *(const u16x8*)&g0[s0];
    const u16x8 ga1 = *(const u16x8*)&g0[s0 + 8];
    const u16x8 gb0 = *(const u16x8*)&g2[s0];
    const u16x8 gb1 = *(const u16x8*)&g2[s0 + 8];
    float a[18], bz[18];
    a[0]  = s0 ? bf2f(g0[s0 - 1]) : 0.f;
    bz[0] = s0 ? bf2f(g2[s0 - 1]) : 0.f;
#pragma unroll
    for (int m = 0; m < 8; ++m) {
      a[1 + m] = bf2f(ga0[m]);  a[9 + m] = bf2f(ga1[m]);
      bz[1 + m] = bf2f(gb0[m]); bz[9 + m] = bf2f(gb1[m]);
    }
    a[17]  = (s0 + 16 < 8192) ? bf2f(g0[s0 + 16]) : 0.f;
    bz[17] = (s0 + 16 < 8192) ? bf2f(g2[s0 + 16]) : 0.f;
#pragma unroll
    for (int m = 0; m < 16; ++m) {
      const float s1v = t00 * a[m] + t01 * a[m + 1] + t02 * a[m + 2] + bs0;
      const float vvv = t20 * bz[m] + t21 * bz[m + 1] + t22 * bz[m + 2] + bs2;
      const float hcv = q0 * bz[m] + q1 * bz[m + 1] + q2 * bz[m + 2] + bc1;
      z[LPZ(s0 + m)] = make_float2(hcv, s1v * vvv);
    }
  }
  __syncthreads();

  fwd8192<512>(z, tw, tid);

  // two-for-one unpack
  float hm[9], yr[9], yi[9];
#pragma unroll
  for (int j = 0; j < 9; ++j) {
    const int k = tid + j * 512;
    if (k <= 4096) {
      const float2 Zk = z[LPZ(BREV13(k))];
      const float2 Zm = z[LPZ(BREV13((8192 - k) & 8191))];
      const float hcr = 0.5f * (Zk.x + Zm.x), hci = 0.5f * (Zk.y - Zm.y);
      hm[j] = sqrtf(hcr * hcr + hci * hci);
      yr[j] = 0.5f * (Zk.y + Zm.y);
      yi[j] = 0.5f * (Zm.x - Zk.x);
    }
  }
  __syncthreads();
  float* hbuf = (float*)z;
#pragma unroll
  for (int j = 0; j < 9; ++j) { const int k = tid + j * 512; if (k <= 4096) hbuf[k] = hm[j]; }
  __syncthreads();

  // h_adapt + G = Y * (h0f + ha)
  const float c0 = w_cond2[d * 3], c1 = w_cond2[d * 3 + 1], c2 = w_cond2[d * 3 + 2], bb2 = b_cond2[d];
  const float2* H0 = h0f + (size_t)d * 4097;
  float gr[9], gi[9];
#pragma unroll
  for (int j = 0; j < 9; ++j) {
    const int k = tid + j * 512;
    if (k <= 4096) {
      const float a = k ? hbuf[k - 1] : 0.f;
      const float m = hbuf[k];
      const float zn = (k < 4096) ? hbuf[k + 1] : 0.f;
      const float ha = c0 * a + c1 * m + c2 * zn + bb2;
      const float2 h = H0[k];
      const float hr = h.x + ha, hi = h.y;
      gr[j] = yr[j] * hr - yi[j] * hi;
      gi[j] = yr[j] * hi + yi[j] * hr;
      if (k == 0 || k == 4096) gi[j] = 0.f;
    }
  }
  __syncthreads();
#pragma unroll
  for (int j = 0; j < 9; ++j) {
    const int k = tid + j * 512;
    if (k <= 4096) z[LPZ(k)] = make_float2(gr[j], gi[j]);
  }
  __syncthreads();

  // half-size packing, store conj(Zc) bit-reversed
  float zr2[8], zi2[8];
#pragma unroll
  for (int j = 0; j < 8; ++j) {
    const int kc = tid + j * 512;
    const float2 Ga = z[LPZ(kc)];
    const float2 Gb = z[LPZ(4096 - kc)];
    const float Er = 0.5f * (Ga.x + Gb.x), Ei = 0.5f * (Ga.y - Gb.y);
    const float Pr = 0.5f * (Ga.x - Gb.x), Pi = 0.5f * (Ga.y + Gb.y);
    const float2 w = tw[kc];
    const float Or = Pr * w.x + Pi * w.y;
    const float Oi = Pi * w.x - Pr * w.y;
    zr2[j] = Er - Oi;
    zi2[j] = -(Ei + Or);
  }
  __syncthreads();
#pragma unroll
  for (int j = 0; j < 8; ++j) {
    const int kc = tid + j * 512;
    z[LPZ(BREV12(kc))] = make_float2(zr2[j], zi2[j]);
  }
  __syncthreads();

  // T14: issue g1 loads now; HBM latency hides under inv4096
  const u16x8 g1a = *(const u16x8*)&g1[s0];
  const u16x8 g1b = *(const u16x8*)&g1[s0 + 8];
  const float ge0 = s0 ? bf2f(g1[s0 - 1]) : 0.f;
  const float ge1 = (s0 + 16 < 8192) ? bf2f(g1[s0 + 16]) : 0.f;

  inv4096<512>(z, tw, tid);

  // final: y2 = irfft * conv3(g1,ws1) -> g0 (bf16)
  {
    float gg[18];
    gg[0] = ge0;
#pragma unroll
    for (int m = 0; m < 8; ++m) { gg[1 + m] = bf2f(g1a[m]); gg[9 + m] = bf2f(g1b[m]); }
    gg[17] = ge1;
    float2 zv[8];
#pragma unroll
    for (int r = 0; r < 8; ++r) zv[r] = z[LPZ((s0 >> 1) + r)];
    const float invM = 1.0f / 4096.0f;
    u16x8 o0, o1;
#pragma unroll
    for (int m = 0; m < 16; ++m) {
      const float xs = ((m & 1) ? -zv[m >> 1].y : zv[m >> 1].x) * invM;
      const float s2v = t10 * gg[m] + t11 * gg[m + 1] + t12 * gg[m + 2] + bs1;
      const u16 val = f2bf(xs * s2v);
      if (m < 8) o0[m] = val; else o1[m - 8] = val;
    }
    *(u16x8*)&g0[s0] = o0;
    *(u16x8*)&g0[s0 + 8] = o1;
  }
}

// ---------------------------------------------------------------- y2 transpose, vectorized u16x8 both sides
__global__ __launch_bounds__(256) void y2tv(const u16* __restrict__ Yr, u16* __restrict__ y2b,
                                            size_t in_str, size_t out_str) {
  __shared__ __align__(16) u16 T[4096];
  Yr  += (size_t)blockIdx.z * in_str;
  y2b += (size_t)blockIdx.z * out_str;
  const int d0 = blockIdx.x * 64, s0 = blockIdx.y * 64;
  const int t = threadIdx.x;
  const int r = t >> 2;
  const int c0 = t & 3;
#pragma unroll
  for (int h = 0; h < 2; ++h) {
    const int cc = c0 + h * 4;
    const u16x8 v = *(const u16x8*)&Yr[(size_t)(d0 + r) * 8192 + s0 + cc * 8];
#pragma unroll
    for (int q = 0; q < 8; ++q) {
      const int s = cc * 8 + q;
      T[s * 64 + (((r >> 3) ^ (s & 7)) << 3) + (r & 7)] = v[q];
    }
  }
  __syncthreads();
  const int l = t & 63, w = t >> 6;
#pragma unroll
  for (int h = 0; h < 2; ++h) {
    const int s = (w + h * 4) * 8 + (l >> 3);
    const int j = l & 7;
    const u16x8 o = *(const u16x8*)&T[s * 64 + ((j ^ (s & 7)) << 3)];
    *(u16x8*)&y2b[(size_t)(s0 + s) * 768 + d0 + j * 8] = o;
  }
}

// ---------------------------------------------------------------- launch
extern "C" void kernel_launch(void* const* d_in, const int* in_sizes, int n_in,
                              void* d_out, int out_size, void* d_ws, size_t ws_size,
                              hipStream_t stream) {
  (void)in_sizes; (void)n_in; (void)out_size;
  const float* x       = (const float*)d_in[0];
  const float* w_in    = (const float*)d_in[1];
  const float* b_in    = (const float*)d_in[2];
  const float* w_short = (const float*)d_in[3];
  const float* b_short = (const float*)d_in[4];
  const float* w_cond1 = (const float*)d_in[5];
  const float* b_cond1 = (const float*)d_in[6];
  const float* w_cond2 = (const float*)d_in[7];
  const float* b_cond2 = (const float*)d_in[8];
  const float* h0      = (const float*)d_in[9];
  const float* w_out   = (const float*)d_in[10];
  const float* b_out   = (const float*)d_in[11];

  float* ws = (float*)d_ws;
  float2* tw  = (float2*)ws;                      // [0, 16384)
  float2* h0f = (float2*)(ws + 16384);            // [16384, 6309376)
  float*  h0T = ws + 6309376;                     // transient (24 MB), consumed early
  const size_t BSTR = 18874368ull;                // u16 per x3T batch
  const size_t XSTR = 6291456ull;                 // u16 per x batch

  const bool t1 = ws_size >= 231282688ull;
  const bool t2 = !t1 && ws_size >= 193533952ull;

  twfill<<<32, 256, 0, stream>>>(tw);
  transp<<<dim3(12, 128), 256, 0, stream>>>(h0, h0T);
  fft_h0_pair<<<384, 512, 0, stream>>>(h0T, tw, h0f);

  if (t1) {
    u16* xb4    = (u16*)(ws + 6309376);
    u16* w_inb  = (u16*)(ws + 18892288);
    u16* w_outb = (u16*)(ws + 19777024);
    u16* x3Tb4  = (u16*)(ws + 20071936);
    cvt_bf16<<<864, 256, 0, stream>>>(w_in, w_inb, 221184);
    cvt_bf16<<<288, 256, 0, stream>>>(w_out, w_outb, 73728);
    cvt_bf16<<<12288, 256, 0, stream>>>(x, xb4, 3145728);
    gemm_bt<1><<<dim3(64, 18, 4), 256, 0, stream>>>(w_inb, xb4, b_in, x3Tb4,
                                                    8192, 768, 0, XSTR, BSTR);
    fused_fft<<<dim3(768, 4), 512, 0, stream>>>(x3Tb4, tw, h0f,
                                                w_short, b_short, w_cond1, b_cond1,
                                                w_cond2, b_cond2, BSTR);
    y2tv<<<dim3(12, 128, 4), 256, 0, stream>>>(x3Tb4, x3Tb4 + XSTR, BSTR, BSTR);
    gemm_bt<0><<<dim3(6, 64, 4), 256, 0, stream>>>(x3Tb4 + XSTR, w_outb, b_out,
                                                   (float*)d_out, 768, 768,
                                                   BSTR, 0, XSTR);
  } else if (t2) {
    u16* xb     = (u16*)(ws + 6309376);
    u16* w_inb  = (u16*)(ws + 9455104);
    u16* w_outb = (u16*)(ws + 10339840);
    u16* x3Tb   = (u16*)(ws + 10634752);
    cvt_bf16<<<864, 256, 0, stream>>>(w_in, w_inb, 221184);
    cvt_bf16<<<288, 256, 0, stream>>>(w_out, w_outb, 73728);
    for (int b = 0; b < 4; ++b) {
      cvt_bf16<<<3072, 256, 0, stream>>>(x + (size_t)b * XSTR, xb, 786432);
      gemm_bt<1><<<dim3(64, 18), 256, 0, stream>>>(w_inb, xb, b_in,
                                                   x3Tb + (size_t)b * BSTR, 8192, 768, 0, 0, 0);
    }
    fused_fft<<<dim3(768, 4), 512, 0, stream>>>(x3Tb, tw, h0f,
                                                w_short, b_short, w_cond1, b_cond1,
                                                w_cond2, b_cond2, BSTR);
    y2tv<<<dim3(12, 128, 4), 256, 0, stream>>>(x3Tb, x3Tb + XSTR, BSTR, BSTR);
    gemm_bt<0><<<dim3(6, 64, 4), 256, 0, stream>>>(x3Tb + XSTR, w_outb, b_out,
                                                   (float*)d_out, 768, 768,
                                                   BSTR, 0, XSTR);
  } else {
    u16* xb     = (u16*)(ws + 6309376);
    u16* w_inb  = (u16*)(ws + 9455104);
    u16* w_outb = (u16*)(ws + 10339840);
    u16* x3Tb   = (u16*)(ws + 10634752);
    cvt_bf16<<<864, 256, 0, stream>>>(w_in, w_inb, 221184);
    cvt_bf16<<<288, 256, 0, stream>>>(w_out, w_outb, 73728);
    for (int b = 0; b < 4; ++b) {
      cvt_bf16<<<3072, 256, 0, stream>>>(x + (size_t)b * XSTR, xb, 786432);
      gemm_bt<1><<<dim3(64, 18), 256, 0, stream>>>(w_inb, xb, b_in, x3Tb, 8192, 768, 0, 0, 0);
      fused_fft<<<dim3(768, 1), 512, 0, stream>>>(x3Tb, tw, h0f,
                                                  w_short, b_short, w_cond1, b_cond1,
                                                  w_cond2, b_cond2, 0);
      y2tv<<<dim3(12, 128, 1), 256, 0, stream>>>(x3Tb, x3Tb + XSTR, 0, 0);
      gemm_bt<0><<<dim3(6, 64, 1), 256, 0, stream>>>(x3Tb + XSTR, w_outb, b_out,
                                                     (float*)d_out + (size_t)b * XSTR,
                                                     768, 768, 0, 0, 0);
    }
  }
}

// Round 20
// 515.775 us; speedup vs baseline: 1.0800x; 1.0163x over previous
//
#include <hip/hip_runtime.h>
#include <math.h>

// B=4, S=8192, D=768, W=3D=2304
// Three ws layouts by ws_size: T1 231.3MB | T2 193.5MB | T3 80.3MB (see R15).
// fused_fft: R19 shell (512 thr, 64 KiB static, fwd {5,3,1} tail fused) + R20
// mirror-paired middle section: G-store + pack-load round trip eliminated.

typedef unsigned short u16;
typedef short s16x8 __attribute__((ext_vector_type(8)));
typedef float f32x4 __attribute__((ext_vector_type(4)));
typedef u16 u16x8 __attribute__((ext_vector_type(8)));

#define LPZ(i) ((i) ^ (((i) >> 4) & 15) ^ (((i) >> 8) & 15))
#define BREV13(k) ((int)(__brev((unsigned)(k)) >> 19))
#define BREV12(k) ((int)(__brev((unsigned)(k)) >> 20))
#define CMUL(rr, ri, xr, xi, wr, wi) { rr = (xr)*(wr) - (xi)*(wi); ri = (xr)*(wi) + (xi)*(wr); }

__device__ __forceinline__ u16 f2bf(float f) {
  unsigned u = __float_as_uint(f);
  u = (u + 0x7FFFu + ((u >> 16) & 1u)) >> 16;
  return (u16)u;
}
__device__ __forceinline__ float bf2f(u16 u) { return __uint_as_float(((unsigned)u) << 16); }

__device__ __forceinline__ void glds16(const void* g, void* l) {
  __builtin_amdgcn_global_load_lds((const __attribute__((address_space(1))) unsigned*)g,
                                   (__attribute__((address_space(3))) unsigned*)l, 16, 0, 0);
}

// ---------------------------------------------------------------- float -> bf16
__global__ __launch_bounds__(256) void cvt_bf16(const float* __restrict__ in,
                                                u16* __restrict__ out, int n8) {
  const int i = blockIdx.x * 256 + threadIdx.x;
  if (i < n8) {
    const float4 a = ((const float4*)in)[i * 2];
    const float4 b = ((const float4*)in)[i * 2 + 1];
    u16x8 r;
    r[0] = f2bf(a.x); r[1] = f2bf(a.y); r[2] = f2bf(a.z); r[3] = f2bf(a.w);
    r[4] = f2bf(b.x); r[5] = f2bf(b.y); r[6] = f2bf(b.z); r[7] = f2bf(b.w);
    ((u16x8*)out)[i] = r;
  }
}

// ---------------------------------------------------------------- MFMA GEMM (glds16 both operands)
template <int BIAS_M>
__global__ __launch_bounds__(256) void gemm_bt(const u16* __restrict__ A,
                                               const u16* __restrict__ B,
                                               const float* __restrict__ bias,
                                               void* __restrict__ Cout,
                                               int N, int K,
                                               size_t As_str, size_t Bs_str, size_t Cs_str) {
  __shared__ __align__(16) u16 As[4096];
  __shared__ __align__(16) u16 Bs[4096];
  A += (size_t)blockIdx.z * As_str;
  B += (size_t)blockIdx.z * Bs_str;
  const int tid = threadIdx.x;
  const int w = tid >> 6, l = tid & 63;
  const int m0 = blockIdx.y * 128, n0 = blockIdx.x * 128;
  const int wr = w >> 1, wc = w & 1;
  const int lr = l & 15, kc = l >> 4;

  const int p0 = w * 64 + l;
  const int p1 = p0 + 256;
  const int sl0 = (p0 & 7) ^ ((p0 >> 3) & 7);
  const int sl1 = (p1 & 7) ^ ((p1 >> 3) & 7);
  const int r0 = ((p0 >> 3) << 1) | (sl0 >> 2), ka = (sl0 & 3) << 3;
  const int r1 = ((p1 >> 3) << 1) | (sl1 >> 2), kb = (sl1 & 3) << 3;
  const u16* gA0 = A + (size_t)(m0 + r0) * K + ka;
  const u16* gA1 = A + (size_t)(m0 + r1) * K + kb;
  const u16* gB0 = B + (size_t)(n0 + r0) * K + ka;
  const u16* gB1 = B + (size_t)(n0 + r1) * K + kb;
  u16* lA0 = &As[(size_t)w * 512];
  u16* lA1 = &As[(size_t)(4 + w) * 512];
  u16* lB0 = &Bs[(size_t)w * 512];
  u16* lB1 = &Bs[(size_t)(4 + w) * 512];

  f32x4 acc[4][4] = {};

  for (int k0 = 0; k0 < K; k0 += 32) {
    glds16(gA0 + k0, lA0);
    glds16(gA1 + k0, lA1);
    glds16(gB0 + k0, lB0);
    glds16(gB1 + k0, lB1);
    __syncthreads();
    s16x8 af[4], bfr[4];
#pragma unroll
    for (int mi = 0; mi < 4; ++mi) {
      const int row = wr * 64 + mi * 16 + lr;
      const int slot = (((lr & 1) << 2) | kc) ^ ((lr >> 1) & 7);
      af[mi] = *(const s16x8*)&As[(row >> 1) * 64 + slot * 8];
    }
#pragma unroll
    for (int ni = 0; ni < 4; ++ni) {
      const int row = wc * 64 + ni * 16 + lr;
      const int slot = (((lr & 1) << 2) | kc) ^ ((lr >> 1) & 7);
      bfr[ni] = *(const s16x8*)&Bs[(row >> 1) * 64 + slot * 8];
    }
#pragma unroll
    for (int mi = 0; mi < 4; ++mi)
#pragma unroll
      for (int ni = 0; ni < 4; ++ni)
        acc[mi][ni] = __builtin_amdgcn_mfma_f32_16x16x32_bf16(af[mi], bfr[ni], acc[mi][ni], 0, 0, 0);
    __syncthreads();
  }

  const int rbase = m0 + wr * 64 + (kc << 2);
  const int cbase = n0 + wc * 64 + lr;
#pragma unroll
  for (int mi = 0; mi < 4; ++mi)
#pragma unroll
    for (int j = 0; j < 4; ++j) {
      const int row = rbase + mi * 16 + j;
      const float bm = BIAS_M ? bias[row] : 0.f;
#pragma unroll
      for (int ni = 0; ni < 4; ++ni) {
        const int col = cbase + ni * 16;
        const float v = acc[mi][ni][j] + (BIAS_M ? bm : bias[col]);
        if (BIAS_M) ((u16*)Cout)[(size_t)blockIdx.z * Cs_str + (size_t)row * N + col] = f2bf(v);
        else ((float*)Cout)[(size_t)blockIdx.z * Cs_str + (size_t)row * N + col] = v;
      }
    }
}

// ---------------------------------------------------------------- twiddles exp(-2pi i k/8192)
__global__ void twfill(float2* __restrict__ tw) {
  const int k = blockIdx.x * 256 + threadIdx.x;
  if (k < 8192) {
    const double t = -2.0 * 3.14159265358979323846 * (double)k / 8192.0;
    tw[k] = make_float2((float)cos(t), (float)sin(t));
  }
}

// ---------------------------------------------------------------- h0 (8192 x 768) -> h0T (768 x 8192) fp32
__global__ __launch_bounds__(256) void transp(const float* __restrict__ in, float* __restrict__ out) {
  __shared__ float T[64][65];
  const int d0 = blockIdx.x * 64, s0 = blockIdx.y * 64;
  const int c = threadIdx.x & 63, r0 = threadIdx.x >> 6;
#pragma unroll
  for (int i = 0; i < 16; ++i) {
    const int r = r0 + i * 4;
    T[r][c] = in[(size_t)(s0 + r) * 768 + d0 + c];
  }
  __syncthreads();
#pragma unroll
  for (int i = 0; i < 16; ++i) {
    const int r = r0 + i * 4;
    out[(size_t)(d0 + r) * 8192 + s0 + c] = T[c][r];
  }
}

// ---------------------------------------------------------------- butterfly bodies
__device__ __forceinline__ void dif4(float2& A, float2& B, float2& C, float2& D,
                                     float2 w1, float2 w2, float2 w3) {
  const float apr = A.x + C.x, api = A.y + C.y, amr = A.x - C.x, ami = A.y - C.y;
  const float bpr = B.x + D.x, bpi = B.y + D.y, bmr = B.x - D.x, bmi = B.y - D.y;
  const float2 o0 = make_float2(apr + bpr, api + bpi);
  const float x1r = apr - bpr, x1i = api - bpi;
  float2 o1; CMUL(o1.x, o1.y, x1r, x1i, w2.x, w2.y);
  const float x2r = amr + bmi, x2i = ami - bmr;
  float2 o2; CMUL(o2.x, o2.y, x2r, x2i, w1.x, w1.y);
  const float x3r = amr - bmi, x3i = ami + bmr;
  float2 o3; CMUL(o3.x, o3.y, x3r, x3i, w3.x, w3.y);
  A = o0; B = o1; C = o2; D = o3;
}

__device__ __forceinline__ void dit4(float2& A, float2& B, float2& C, float2& D,
                                     float2 w1, float2 w2) {
  float vbr, vbi, vdr, vdi;
  CMUL(vbr, vbi, B.x, B.y, w2.x, w2.y);
  CMUL(vdr, vdi, D.x, D.y, w2.x, w2.y);
  const float a1r = A.x + vbr, a1i = A.y + vbi;
  const float b1r = A.x - vbr, b1i = A.y - vbi;
  const float c1r = C.x + vdr, c1i = C.y + vdi;
  const float d1r = C.x - vdr, d1i = C.y - vdi;
  float t1r, t1i, ur, ui;
  CMUL(t1r, t1i, c1r, c1i, w1.x, w1.y);
  CMUL(ur, ui, d1r, d1i, w1.y, -w1.x);
  A = make_float2(a1r + t1r, a1i + t1i);
  C = make_float2(a1r - t1r, a1i - t1i);
  B = make_float2(b1r + ur,  b1i + ui);
  D = make_float2(b1r - ur,  b1i - ui);
}

// ---------------------------------------------------------------- radix-16 passes
__device__ __forceinline__ void fwd_pass16(float2* z, const float2* __restrict__ tw,
                                           int base, int jp, int st, int e) {
  float2 v[16]; int idx[16];
#pragma unroll
  for (int m = 0; m < 16; ++m) { idx[m] = LPZ(base + m * st); v[m] = z[idx[m]]; }
#pragma unroll
  for (int c = 0; c < 4; ++c) {
    const int jc = jp + c * st;
    dif4(v[c], v[c + 4], v[c + 8], v[c + 12],
         tw[jc << e], tw[(2 * jc) << e], tw[(3 * jc) << e]);
  }
  const float2 u1 = tw[jp << (e + 2)];
  const float2 u2 = tw[(2 * jp) << (e + 2)];
  const float2 u3 = tw[(3 * jp) << (e + 2)];
#pragma unroll
  for (int a = 0; a < 4; ++a)
    dif4(v[4 * a], v[4 * a + 1], v[4 * a + 2], v[4 * a + 3], u1, u2, u3);
#pragma unroll
  for (int m = 0; m < 16; ++m) z[idx[m]] = v[m];
}

__device__ __forceinline__ void inv_pass16(float2* z, const float2* __restrict__ tw,
                                           int base, int jp, int st, int e) {
  float2 v[16]; int idx[16];
#pragma unroll
  for (int m = 0; m < 16; ++m) { idx[m] = LPZ(base + m * st); v[m] = z[idx[m]]; }
  const float2 w1 = tw[jp << e];
  const float2 w2 = tw[(2 * jp) << e];
#pragma unroll
  for (int a = 0; a < 4; ++a)
    dit4(v[4 * a], v[4 * a + 1], v[4 * a + 2], v[4 * a + 3], w1, w2);
#pragma unroll
  for (int c = 0; c < 4; ++c) {
    const int jpp = c * st + jp;
    dit4(v[c], v[c + 4], v[c + 8], v[c + 12],
         tw[jpp << (e - 2)], tw[(2 * jpp) << (e - 2)]);
  }
#pragma unroll
  for (int m = 0; m < 16; ++m) z[idx[m]] = v[m];
}

// ---------------------------------------------------------------- forward 8192: 2 radix-16 + fused {5,3,1} tail
template <int NT>
__device__ __forceinline__ void fwd8192(float2* z, const float2* __restrict__ tw, int tid) {
  fwd_pass16(z, tw, tid, tid, 512, 0);                                  // stages 13,11
  __syncthreads();
  fwd_pass16(z, tw, ((tid >> 5) << 9) | (tid & 31), tid & 31, 32, 4);   // stages 9,7
  __syncthreads();
  if (tid < 256) {                                                      // stages 5,3,1
    float2 v[32];
#pragma unroll
    for (int n = 0; n < 32; ++n) v[n] = z[LPZ(tid * 32 + n)];
#pragma unroll
    for (int p = 0; p < 8; ++p)
      dif4(v[p], v[p + 8], v[p + 16], v[p + 24],
           tw[p << 8], tw[(2 * p) << 8], tw[(3 * p) << 8]);
    const float2 one = make_float2(1.f, 0.f);
    const float2 o1 = tw[1 << 10], o2 = tw[2 << 10], o3 = tw[3 << 10];
#pragma unroll
    for (int a = 0; a < 4; ++a) {
      dif4(v[8 * a], v[8 * a + 2], v[8 * a + 4], v[8 * a + 6], one, one, one);
      dif4(v[8 * a + 1], v[8 * a + 3], v[8 * a + 5], v[8 * a + 7], o1, o2, o3);
    }
#pragma unroll
    for (int i = 0; i < 16; ++i) {
      const float2 U = v[2 * i], V = v[2 * i + 1];
      v[2 * i]     = make_float2(U.x + V.x, U.y + V.y);
      v[2 * i + 1] = make_float2(U.x - V.x, U.y - V.y);
    }
#pragma unroll
    for (int n = 0; n < 32; ++n) z[LPZ(tid * 32 + n)] = v[n];
  }
  __syncthreads();
}

// ---------------------------------------------------------------- inverse-core 4096: 3 radix-16
template <int NT>
__device__ __forceinline__ void inv4096(float2* z, const float2* __restrict__ tw, int tid) {
  if (tid < 256) inv_pass16(z, tw, tid << 4, 0, 1, 11);
  __syncthreads();
  if (tid < 256) inv_pass16(z, tw, ((tid >> 4) << 8) | (tid & 15), tid & 15, 16, 7);
  __syncthreads();
  if (tid < 256) inv_pass16(z, tw, tid, tid, 256, 3);
  __syncthreads();
}

// ---------------------------------------------------------------- paired h0 FFT
__global__ __launch_bounds__(512, 2) void fft_h0_pair(const float* __restrict__ h0T,
                                                      const float2* __restrict__ tw,
                                                      float2* __restrict__ h0f) {
  __shared__ float2 z[8192];
  const int d0 = blockIdx.x * 2, tid = threadIdx.x;
  const float* srcA = h0T + (size_t)d0 * 8192;
  const float* srcB = srcA + 8192;
  const int s0 = tid << 4;
#pragma unroll
  for (int m = 0; m < 16; ++m) z[LPZ(s0 + m)] = make_float2(srcA[s0 + m], srcB[s0 + m]);
  __syncthreads();
  fwd8192<512>(z, tw, tid);
  float2* H0 = h0f + (size_t)d0 * 4097;
  float2* H1 = H0 + 4097;
  for (int k = tid; k <= 4096; k += 512) {
    const float2 Zk = z[LPZ(BREV13(k))];
    const float2 Zm = z[LPZ(BREV13((8192 - k) & 8191))];
    H0[k] = make_float2(0.5f * (Zk.x + Zm.x), 0.5f * (Zk.y - Zm.y));
    H1[k] = make_float2(0.5f * (Zk.y + Zm.y), 0.5f * (Zm.x - Zk.x));
  }
}

// ---------------------------------------------------------------- fused per-(b,d) row pipeline
__global__ __launch_bounds__(512, 2) void fused_fft(u16* __restrict__ x3T,
                                                    const float2* __restrict__ tw,
                                                    const float2* __restrict__ h0f,
                                                    const float* __restrict__ w_short,
                                                    const float* __restrict__ b_short,
                                                    const float* __restrict__ w_cond1,
                                                    const float* __restrict__ b_cond1,
                                                    const float* __restrict__ w_cond2,
                                                    const float* __restrict__ b_cond2,
                                                    size_t bstr) {
  __shared__ float2 z[8192];
  const int d = blockIdx.x, tid = threadIdx.x;
  x3T += (size_t)blockIdx.y * bstr;
  u16* g0 = x3T + (size_t)d * 8192;
  const u16* g1 = x3T + (size_t)(768 + d) * 8192;
  const u16* g2 = x3T + (size_t)(1536 + d) * 8192;

  const float q0 = w_cond1[d * 3], q1 = w_cond1[d * 3 + 1], q2 = w_cond1[d * 3 + 2], bc1 = b_cond1[d];
  const float t00 = w_short[d * 3], t01 = w_short[d * 3 + 1], t02 = w_short[d * 3 + 2], bs0 = b_short[d];
  const float t10 = w_short[(768 + d) * 3], t11 = w_short[(768 + d) * 3 + 1], t12 = w_short[(768 + d) * 3 + 2], bs1 = b_short[768 + d];
  const float t20 = w_short[(1536 + d) * 3], t21 = w_short[(1536 + d) * 3 + 1], t22 = w_short[(1536 + d) * 3 + 2], bs2 = b_short[1536 + d];

  const int s0 = tid << 4;

  // conv phase (global -> regs -> z): z[s] = hc[s] + i*y[s]
  {
    const u16x8 ga0 = *(const u16x8*)&g0[s0];
    const u16x8 ga1 = *(const u16x8*)&g0[s0 + 8];
    const u16x8 gb0 = *(const u16x8*)&g2[s0];
    const u16x8 gb1 = *(const u16x8*)&g2[s0 + 8];
    float a[18], bz[18];
    a[0]  = s0 ? bf2f(g0[s0 - 1]) : 0.f;
    bz[0] = s0 ? bf2f(g2[s0 - 1]) : 0.f;
#pragma unroll
    for (int m = 0; m < 8; ++m) {
      a[1 + m] = bf2f(ga0[m]);  a[9 + m] = bf2f(ga1[m]);
      bz[1 + m] = bf2f(gb0[m]); bz[9 + m] = bf2f(gb1[m]);
    }
    a[17]  = (s0 + 16 < 8192) ? bf2f(g0[s0 + 16]) : 0.f;
    bz[17] = (s0 + 16 < 8192) ? bf2f(g2[s0 + 16]) : 0.f;
#pragma unroll
    for (int m = 0; m < 16; ++m) {
      const float s1v = t00 * a[m] + t01 * a[m + 1] + t02 * a[m + 2] + bs0;
      const float vvv = t20 * bz[m] + t21 * bz[m + 1] + t22 * bz[m + 2] + bs2;
      const float hcv = q0 * bz[m] + q1 * bz[m + 1] + q2 * bz[m + 2] + bc1;
      z[LPZ(s0 + m)] = make_float2(hcv, s1v * vvv);
    }
  }
  __syncthreads();

  fwd8192<512>(z, tw, tid);

  // -------- mirror-paired unpack: thread covers k = kc and k = 4096-kc (kc = tid + j*512 < 2048)
  float hma[4], yra[4], yia[4];   // k = kc
  float hmb[4], yrb[4], yib[4];   // k = 4096-kc
  float hmc = 0.f, yrc = 0.f, yic = 0.f;  // k = 2048 (tid==0)
#pragma unroll
  for (int j = 0; j < 4; ++j) {
    const int kc = tid + j * 512;
    {
      const float2 Zk = z[LPZ(BREV13(kc))];
      const float2 Zm = z[LPZ(BREV13((8192 - kc) & 8191))];
      const float hcr = 0.5f * (Zk.x + Zm.x), hci = 0.5f * (Zk.y - Zm.y);
      hma[j] = sqrtf(hcr * hcr + hci * hci);
      yra[j] = 0.5f * (Zk.y + Zm.y);
      yia[j] = 0.5f * (Zm.x - Zk.x);
    }
    {
      const int k2 = 4096 - kc;
      const float2 Zk = z[LPZ(BREV13(k2))];
      const float2 Zm = z[LPZ(BREV13(4096 + kc))];
      const float hcr = 0.5f * (Zk.x + Zm.x), hci = 0.5f * (Zk.y - Zm.y);
      hmb[j] = sqrtf(hcr * hcr + hci * hci);
      yrb[j] = 0.5f * (Zk.y + Zm.y);
      yib[j] = 0.5f * (Zm.x - Zk.x);
    }
  }
  if (tid == 0) {
    const float2 Zk = z[LPZ(BREV13(2048))];
    const float2 Zm = z[LPZ(BREV13(6144))];
    const float hcr = 0.5f * (Zk.x + Zm.x), hci = 0.5f * (Zk.y - Zm.y);
    hmc = sqrtf(hcr * hcr + hci * hci);
    yrc = 0.5f * (Zk.y + Zm.y);
    yic = 0.5f * (Zm.x - Zk.x);
  }
  __syncthreads();
  float* hbuf = (float*)z;           // linear float scratch [0,4097)
#pragma unroll
  for (int j = 0; j < 4; ++j) {
    const int kc = tid + j * 512;
    hbuf[kc] = hma[j];
    hbuf[4096 - kc] = hmb[j];
  }
  if (tid == 0) hbuf[2048] = hmc;
  __syncthreads();

  // -------- h_adapt + G (both mirrors) + pack -> Zc in regs
  const float c0 = w_cond2[d * 3], c1 = w_cond2[d * 3 + 1], c2 = w_cond2[d * 3 + 2], bb2 = b_cond2[d];
  const float2* H0 = h0f + (size_t)d * 4097;
  float zar[4], zai[4], zbr[4], zbi[4];
  float2 zc2048 = make_float2(0.f, 0.f);
#pragma unroll
  for (int j = 0; j < 4; ++j) {
    const int kc = tid + j * 512;
    const int k2 = 4096 - kc;
    const float aA = kc ? hbuf[kc - 1] : 0.f;
    const float mA = hbuf[kc];
    const float zA = hbuf[kc + 1];
    const float haA = c0 * aA + c1 * mA + c2 * zA + bb2;
    const float aB = hbuf[k2 - 1];
    const float mB = hbuf[k2];
    const float zB = (k2 < 4096) ? hbuf[k2 + 1] : 0.f;
    const float haB = c0 * aB + c1 * mB + c2 * zB + bb2;
    const float2 hA = H0[kc];
    const float hrA = hA.x + haA, hiA = hA.y;
    float grA = yra[j] * hrA - yia[j] * hiA;
    float giA = yra[j] * hiA + yia[j] * hrA;
    if (kc == 0) giA = 0.f;
    const float2 hB = H0[k2];
    const float hrB = hB.x + haB, hiB = hB.y;
    float grB = yrb[j] * hrB - yib[j] * hiB;
    float giB = yrb[j] * hiB + yib[j] * hrB;
    if (k2 == 4096) giB = 0.f;
    const float Er = 0.5f * (grA + grB), Ei = 0.5f * (giA - giB);
    const float Pr = 0.5f * (grA - grB), Pi = 0.5f * (giA + giB);
    const float2 w = tw[kc];
    const float Or = Pr * w.x + Pi * w.y;
    const float Oi = Pi * w.x - Pr * w.y;
    zar[j] = Er - Oi; zai[j] = -(Ei + Or);       // Zc[kc]
    zbr[j] = Er + Oi; zbi[j] = Ei - Or;          // Zc[4096-kc]
  }
  if (tid == 0) {
    const float aC = hbuf[2047], mC = hbuf[2048], zC = hbuf[2049];
    const float haC = c0 * aC + c1 * mC + c2 * zC + bb2;
    const float2 hC = H0[2048];
    const float hrC = hC.x + haC, hiC = hC.y;
    zc2048 = make_float2(yrc * hrC - yic * hiC, yrc * hiC + yic * hrC);  // Zc[2048] = G[2048]
  }
  __syncthreads();
#pragma unroll
  for (int j = 0; j < 4; ++j) {
    const int kc = tid + j * 512;
    z[LPZ(BREV12(kc))] = make_float2(zar[j], zai[j]);
    if (kc) z[LPZ(BREV12(4096 - kc))] = make_float2(zbr[j], zbi[j]);
  }
  if (tid == 0) z[LPZ(BREV12(2048))] = zc2048;
  __syncthreads();

  // T14: issue g1 loads now; HBM latency hides under inv4096
  const u16x8 g1a = *(const u16x8*)&g1[s0];
  const u16x8 g1b = *(const u16x8*)&g1[s0 + 8];
  const float ge0 = s0 ? bf2f(g1[s0 - 1]) : 0.f;
  const float ge1 = (s0 + 16 < 8192) ? bf2f(g1[s0 + 16]) : 0.f;

  inv4096<512>(z, tw, tid);

  // final: y2 = irfft * conv3(g1,ws1) -> g0 (bf16)
  {
    float gg[18];
    gg[0] = ge0;
#pragma unroll
    for (int m = 0; m < 8; ++m) { gg[1 + m] = bf2f(g1a[m]); gg[9 + m] = bf2f(g1b[m]); }
    gg[17] = ge1;
    float2 zv[8];
#pragma unroll
    for (int r = 0; r < 8; ++r) zv[r] = z[LPZ((s0 >> 1) + r)];
    const float invM = 1.0f / 4096.0f;
    u16x8 o0, o1;
#pragma unroll
    for (int m = 0; m < 16; ++m) {
      const float xs = ((m & 1) ? -zv[m >> 1].y : zv[m >> 1].x) * invM;
      const float s2v = t10 * gg[m] + t11 * gg[m + 1] + t12 * gg[m + 2] + bs1;
      const u16 val = f2bf(xs * s2v);
      if (m < 8) o0[m] = val; else o1[m - 8] = val;
    }
    *(u16x8*)&g0[s0] = o0;
    *(u16x8*)&g0[s0 + 8] = o1;
  }
}

// ---------------------------------------------------------------- y2 transpose, vectorized u16x8 both sides
__global__ __launch_bounds__(256) void y2tv(const u16* __restrict__ Yr, u16* __restrict__ y2b,
                                            size_t in_str, size_t out_str) {
  __shared__ __align__(16) u16 T[4096];
  Yr  += (size_t)blockIdx.z * in_str;
  y2b += (size_t)blockIdx.z * out_str;
  const int d0 = blockIdx.x * 64, s0 = blockIdx.y * 64;
  const int t = threadIdx.x;
  const int r = t >> 2;
  const int c0 = t & 3;
#pragma unroll
  for (int h = 0; h < 2; ++h) {
    const int cc = c0 + h * 4;
    const u16x8 v = *(const u16x8*)&Yr[(size_t)(d0 + r) * 8192 + s0 + cc * 8];
#pragma unroll
    for (int q = 0; q < 8; ++q) {
      const int s = cc * 8 + q;
      T[s * 64 + (((r >> 3) ^ (s & 7)) << 3) + (r & 7)] = v[q];
    }
  }
  __syncthreads();
  const int l = t & 63, w = t >> 6;
#pragma unroll
  for (int h = 0; h < 2; ++h) {
    const int s = (w + h * 4) * 8 + (l >> 3);
    const int j = l & 7;
    const u16x8 o = *(const u16x8*)&T[s * 64 + ((j ^ (s & 7)) << 3)];
    *(u16x8*)&y2b[(size_t)(s0 + s) * 768 + d0 + j * 8] = o;
  }
}

// ---------------------------------------------------------------- launch
extern "C" void kernel_launch(void* const* d_in, const int* in_sizes, int n_in,
                              void* d_out, int out_size, void* d_ws, size_t ws_size,
                              hipStream_t stream) {
  (void)in_sizes; (void)n_in; (void)out_size;
  const float* x       = (const float*)d_in[0];
  const float* w_in    = (const float*)d_in[1];
  const float* b_in    = (const float*)d_in[2];
  const float* w_short = (const float*)d_in[3];
  const float* b_short = (const float*)d_in[4];
  const float* w_cond1 = (const float*)d_in[5];
  const float* b_cond1 = (const float*)d_in[6];
  const float* w_cond2 = (const float*)d_in[7];
  const float* b_cond2 = (const float*)d_in[8];
  const float* h0      = (const float*)d_in[9];
  const float* w_out   = (const float*)d_in[10];
  const float* b_out   = (const float*)d_in[11];

  float* ws = (float*)d_ws;
  float2* tw  = (float2*)ws;                      // [0, 16384)
  float2* h0f = (float2*)(ws + 16384);            // [16384, 6309376)
  float*  h0T = ws + 6309376;                     // transient (24 MB), consumed early
  const size_t BSTR = 18874368ull;                // u16 per x3T batch
  const size_t XSTR = 6291456ull;                 // u16 per x batch

  const bool t1 = ws_size >= 231282688ull;
  const bool t2 = !t1 && ws_size >= 193533952ull;

  twfill<<<32, 256, 0, stream>>>(tw);
  transp<<<dim3(12, 128), 256, 0, stream>>>(h0, h0T);
  fft_h0_pair<<<384, 512, 0, stream>>>(h0T, tw, h0f);

  if (t1) {
    u16* xb4    = (u16*)(ws + 6309376);
    u16* w_inb  = (u16*)(ws + 18892288);
    u16* w_outb = (u16*)(ws + 19777024);
    u16* x3Tb4  = (u16*)(ws + 20071936);
    cvt_bf16<<<864, 256, 0, stream>>>(w_in, w_inb, 221184);
    cvt_bf16<<<288, 256, 0, stream>>>(w_out, w_outb, 73728);
    cvt_bf16<<<12288, 256, 0, stream>>>(x, xb4, 3145728);
    gemm_bt<1><<<dim3(64, 18, 4), 256, 0, stream>>>(w_inb, xb4, b_in, x3Tb4,
                                                    8192, 768, 0, XSTR, BSTR);
    fused_fft<<<dim3(768, 4), 512, 0, stream>>>(x3Tb4, tw, h0f,
                                                w_short, b_short, w_cond1, b_cond1,
                                                w_cond2, b_cond2, BSTR);
    y2tv<<<dim3(12, 128, 4), 256, 0, stream>>>(x3Tb4, x3Tb4 + XSTR, BSTR, BSTR);
    gemm_bt<0><<<dim3(6, 64, 4), 256, 0, stream>>>(x3Tb4 + XSTR, w_outb, b_out,
                                                   (float*)d_out, 768, 768,
                                                   BSTR, 0, XSTR);
  } else if (t2) {
    u16* xb     = (u16*)(ws + 6309376);
    u16* w_inb  = (u16*)(ws + 9455104);
    u16* w_outb = (u16*)(ws + 10339840);
    u16* x3Tb   = (u16*)(ws + 10634752);
    cvt_bf16<<<864, 256, 0, stream>>>(w_in, w_inb, 221184);
    cvt_bf16<<<288, 256, 0, stream>>>(w_out, w_outb, 73728);
    for (int b = 0; b < 4; ++b) {
      cvt_bf16<<<3072, 256, 0, stream>>>(x + (size_t)b * XSTR, xb, 786432);
      gemm_bt<1><<<dim3(64, 18), 256, 0, stream>>>(w_inb, xb, b_in,
                                                   x3Tb + (size_t)b * BSTR, 8192, 768, 0, 0, 0);
    }
    fused_fft<<<dim3(768, 4), 512, 0, stream>>>(x3Tb, tw, h0f,
                                                w_short, b_short, w_cond1, b_cond1,
                                                w_cond2, b_cond2, BSTR);
    y2tv<<<dim3(12, 128, 4), 256, 0, stream>>>(x3Tb, x3Tb + XSTR, BSTR, BSTR);
    gemm_bt<0><<<dim3(6, 64, 4), 256, 0, stream>>>(x3Tb + XSTR, w_outb, b_out,
                                                   (float*)d_out, 768, 768,
                                                   BSTR, 0, XSTR);
  } else {
    u16* xb     = (u16*)(ws + 6309376);
    u16* w_inb  = (u16*)(ws + 9455104);
    u16* w_outb = (u16*)(ws + 10339840);
    u16* x3Tb   = (u16*)(ws + 10634752);
    cvt_bf16<<<864, 256, 0, stream>>>(w_in, w_inb, 221184);
    cvt_bf16<<<288, 256, 0, stream>>>(w_out, w_outb, 73728);
    for (int b = 0; b < 4; ++b) {
      cvt_bf16<<<3072, 256, 0, stream>>>(x + (size_t)b * XSTR, xb, 786432);
      gemm_bt<1><<<dim3(64, 18), 256, 0, stream>>>(w_inb, xb, b_in, x3Tb, 8192, 768, 0, 0, 0);
      fused_fft<<<dim3(768, 1), 512, 0, stream>>>(x3Tb, tw, h0f,
                                                  w_short, b_short, w_cond1, b_cond1,
                                                  w_cond2, b_cond2, 0);
      y2tv<<<dim3(12, 128, 1), 256, 0, stream>>>(x3Tb, x3Tb + XSTR, 0, 0);
      gemm_bt<0><<<dim3(6, 64, 1), 256, 0, stream>>>(x3Tb + XSTR, w_outb, b_out,
                                                     (float*)d_out + (size_t)b * XSTR,
                                                     768, 768, 0, 0, 0);
    }
  }
}

// Round 21
// 506.845 us; speedup vs baseline: 1.0990x; 1.0176x over previous
//
#include <hip/hip_runtime.h>
#include <math.h>

// B=4, S=8192, D=768, W=3D=2304
// Tiers by ws_size: T1 231.3MB | T2 193.5MB | T3 80.3MB.
// h0T (fp32 transient) now lives at the START of the x3Tb region in ALL tiers
// (dead until gemm1, which runs after fft_h0_pair consumes it).
// T1 prologue merged into one kernel (cvt_x | cvt_w_in | cvt_w_out | transp | twfill).

typedef unsigned short u16;
typedef short s16x8 __attribute__((ext_vector_type(8)));
typedef float f32x4 __attribute__((ext_vector_type(4)));
typedef u16 u16x8 __attribute__((ext_vector_type(8)));

#define LPZ(i) ((i) ^ (((i) >> 4) & 15) ^ (((i) >> 8) & 15))
#define BREV13(k) ((int)(__brev((unsigned)(k)) >> 19))
#define BREV12(k) ((int)(__brev((unsigned)(k)) >> 20))
#define CMUL(rr, ri, xr, xi, wr, wi) { rr = (xr)*(wr) - (xi)*(wi); ri = (xr)*(wi) + (xi)*(wr); }

__device__ __forceinline__ u16 f2bf(float f) {
  unsigned u = __float_as_uint(f);
  u = (u + 0x7FFFu + ((u >> 16) & 1u)) >> 16;
  return (u16)u;
}
__device__ __forceinline__ float bf2f(u16 u) { return __uint_as_float(((unsigned)u) << 16); }

__device__ __forceinline__ void glds16(const void* g, void* l) {
  __builtin_amdgcn_global_load_lds((const __attribute__((address_space(1))) unsigned*)g,
                                   (__attribute__((address_space(3))) unsigned*)l, 16, 0, 0);
}

__device__ __forceinline__ void cvt8(const float* __restrict__ in, u16* __restrict__ out, int i) {
  const float4 a = ((const float4*)in)[i * 2];
  const float4 b = ((const float4*)in)[i * 2 + 1];
  u16x8 r;
  r[0] = f2bf(a.x); r[1] = f2bf(a.y); r[2] = f2bf(a.z); r[3] = f2bf(a.w);
  r[4] = f2bf(b.x); r[5] = f2bf(b.y); r[6] = f2bf(b.z); r[7] = f2bf(b.w);
  ((u16x8*)out)[i] = r;
}

// ---------------------------------------------------------------- float -> bf16 (standalone, T2/T3)
__global__ __launch_bounds__(256) void cvt_bf16(const float* __restrict__ in,
                                                u16* __restrict__ out, int n8) {
  const int i = blockIdx.x * 256 + threadIdx.x;
  if (i < n8) cvt8(in, out, i);
}

// ---------------------------------------------------------------- twiddles (standalone, T2/T3)
__global__ void twfill(float2* __restrict__ tw) {
  const int k = blockIdx.x * 256 + threadIdx.x;
  if (k < 8192) {
    const double t = -2.0 * 3.14159265358979323846 * (double)k / 8192.0;
    tw[k] = make_float2((float)cos(t), (float)sin(t));
  }
}

// ---------------------------------------------------------------- h0 transpose body
__device__ __forceinline__ void transp_body(const float* __restrict__ in, float* __restrict__ out,
                                            int bx, int by, int tid) {
  __shared__ float T[64][65];
  const int d0 = bx * 64, s0 = by * 64;
  const int c = tid & 63, r0 = tid >> 6;
#pragma unroll
  for (int i = 0; i < 16; ++i) {
    const int r = r0 + i * 4;
    T[r][c] = in[(size_t)(s0 + r) * 768 + d0 + c];
  }
  __syncthreads();
#pragma unroll
  for (int i = 0; i < 16; ++i) {
    const int r = r0 + i * 4;
    out[(size_t)(d0 + r) * 8192 + s0 + c] = T[c][r];
  }
}

__global__ __launch_bounds__(256) void transp(const float* __restrict__ in, float* __restrict__ out) {
  transp_body(in, out, blockIdx.x, blockIdx.y, threadIdx.x);
}

// ---------------------------------------------------------------- merged prologue (T1)
// [0,12288) cvt_x | [12288,13152) cvt w_in | [13152,13440) cvt w_out |
// [13440,14976) transp h0 | [14976,15008) twfill
__global__ __launch_bounds__(256) void prologue_all(const float* __restrict__ x,
                                                    const float* __restrict__ w_in,
                                                    const float* __restrict__ w_out,
                                                    const float* __restrict__ h0,
                                                    float2* __restrict__ tw,
                                                    float* __restrict__ h0T,
                                                    u16* __restrict__ w_inb,
                                                    u16* __restrict__ w_outb,
                                                    u16* __restrict__ xb4) {
  const int b = blockIdx.x, tid = threadIdx.x;
  if (b < 12288) {
    cvt8(x, xb4, b * 256 + tid);
  } else if (b < 13152) {
    const int i = (b - 12288) * 256 + tid;
    if (i < 221184) cvt8(w_in, w_inb, i);
  } else if (b < 13440) {
    const int i = (b - 13152) * 256 + tid;
    if (i < 73728) cvt8(w_out, w_outb, i);
  } else if (b < 14976) {
    const int idx = b - 13440;
    transp_body(h0, h0T, idx % 12, idx / 12, tid);
  } else {
    const int k = (b - 14976) * 256 + tid;
    if (k < 8192) {
      const double t = -2.0 * 3.14159265358979323846 * (double)k / 8192.0;
      tw[k] = make_float2((float)cos(t), (float)sin(t));
    }
  }
}

// ---------------------------------------------------------------- MFMA GEMM (glds16 both operands)
template <int BIAS_M>
__global__ __launch_bounds__(256) void gemm_bt(const u16* __restrict__ A,
                                               const u16* __restrict__ B,
                                               const float* __restrict__ bias,
                                               void* __restrict__ Cout,
                                               int N, int K,
                                               size_t As_str, size_t Bs_str, size_t Cs_str) {
  __shared__ __align__(16) u16 As[4096];
  __shared__ __align__(16) u16 Bs[4096];
  A += (size_t)blockIdx.z * As_str;
  B += (size_t)blockIdx.z * Bs_str;
  const int tid = threadIdx.x;
  const int w = tid >> 6, l = tid & 63;
  const int m0 = blockIdx.y * 128, n0 = blockIdx.x * 128;
  const int wr = w >> 1, wc = w & 1;
  const int lr = l & 15, kc = l >> 4;

  const int p0 = w * 64 + l;
  const int p1 = p0 + 256;
  const int sl0 = (p0 & 7) ^ ((p0 >> 3) & 7);
  const int sl1 = (p1 & 7) ^ ((p1 >> 3) & 7);
  const int r0 = ((p0 >> 3) << 1) | (sl0 >> 2), ka = (sl0 & 3) << 3;
  const int r1 = ((p1 >> 3) << 1) | (sl1 >> 2), kb = (sl1 & 3) << 3;
  const u16* gA0 = A + (size_t)(m0 + r0) * K + ka;
  const u16* gA1 = A + (size_t)(m0 + r1) * K + kb;
  const u16* gB0 = B + (size_t)(n0 + r0) * K + ka;
  const u16* gB1 = B + (size_t)(n0 + r1) * K + kb;
  u16* lA0 = &As[(size_t)w * 512];
  u16* lA1 = &As[(size_t)(4 + w) * 512];
  u16* lB0 = &Bs[(size_t)w * 512];
  u16* lB1 = &Bs[(size_t)(4 + w) * 512];

  f32x4 acc[4][4] = {};

  for (int k0 = 0; k0 < K; k0 += 32) {
    glds16(gA0 + k0, lA0);
    glds16(gA1 + k0, lA1);
    glds16(gB0 + k0, lB0);
    glds16(gB1 + k0, lB1);
    __syncthreads();
    s16x8 af[4], bfr[4];
#pragma unroll
    for (int mi = 0; mi < 4; ++mi) {
      const int row = wr * 64 + mi * 16 + lr;
      const int slot = (((lr & 1) << 2) | kc) ^ ((lr >> 1) & 7);
      af[mi] = *(const s16x8*)&As[(row >> 1) * 64 + slot * 8];
    }
#pragma unroll
    for (int ni = 0; ni < 4; ++ni) {
      const int row = wc * 64 + ni * 16 + lr;
      const int slot = (((lr & 1) << 2) | kc) ^ ((lr >> 1) & 7);
      bfr[ni] = *(const s16x8*)&Bs[(row >> 1) * 64 + slot * 8];
    }
#pragma unroll
    for (int mi = 0; mi < 4; ++mi)
#pragma unroll
      for (int ni = 0; ni < 4; ++ni)
        acc[mi][ni] = __builtin_amdgcn_mfma_f32_16x16x32_bf16(af[mi], bfr[ni], acc[mi][ni], 0, 0, 0);
    __syncthreads();
  }

  const int rbase = m0 + wr * 64 + (kc << 2);
  const int cbase = n0 + wc * 64 + lr;
#pragma unroll
  for (int mi = 0; mi < 4; ++mi)
#pragma unroll
    for (int j = 0; j < 4; ++j) {
      const int row = rbase + mi * 16 + j;
      const float bm = BIAS_M ? bias[row] : 0.f;
#pragma unroll
      for (int ni = 0; ni < 4; ++ni) {
        const int col = cbase + ni * 16;
        const float v = acc[mi][ni][j] + (BIAS_M ? bm : bias[col]);
        if (BIAS_M) ((u16*)Cout)[(size_t)blockIdx.z * Cs_str + (size_t)row * N + col] = f2bf(v);
        else ((float*)Cout)[(size_t)blockIdx.z * Cs_str + (size_t)row * N + col] = v;
      }
    }
}

// ---------------------------------------------------------------- butterfly bodies
__device__ __forceinline__ void dif4(float2& A, float2& B, float2& C, float2& D,
                                     float2 w1, float2 w2, float2 w3) {
  const float apr = A.x + C.x, api = A.y + C.y, amr = A.x - C.x, ami = A.y - C.y;
  const float bpr = B.x + D.x, bpi = B.y + D.y, bmr = B.x - D.x, bmi = B.y - D.y;
  const float2 o0 = make_float2(apr + bpr, api + bpi);
  const float x1r = apr - bpr, x1i = api - bpi;
  float2 o1; CMUL(o1.x, o1.y, x1r, x1i, w2.x, w2.y);
  const float x2r = amr + bmi, x2i = ami - bmr;
  float2 o2; CMUL(o2.x, o2.y, x2r, x2i, w1.x, w1.y);
  const float x3r = amr - bmi, x3i = ami + bmr;
  float2 o3; CMUL(o3.x, o3.y, x3r, x3i, w3.x, w3.y);
  A = o0; B = o1; C = o2; D = o3;
}

__device__ __forceinline__ void dit4(float2& A, float2& B, float2& C, float2& D,
                                     float2 w1, float2 w2) {
  float vbr, vbi, vdr, vdi;
  CMUL(vbr, vbi, B.x, B.y, w2.x, w2.y);
  CMUL(vdr, vdi, D.x, D.y, w2.x, w2.y);
  const float a1r = A.x + vbr, a1i = A.y + vbi;
  const float b1r = A.x - vbr, b1i = A.y - vbi;
  const float c1r = C.x + vdr, c1i = C.y + vdi;
  const float d1r = C.x - vdr, d1i = C.y - vdi;
  float t1r, t1i, ur, ui;
  CMUL(t1r, t1i, c1r, c1i, w1.x, w1.y);
  CMUL(ur, ui, d1r, d1i, w1.y, -w1.x);
  A = make_float2(a1r + t1r, a1i + t1i);
  C = make_float2(a1r - t1r, a1i - t1i);
  B = make_float2(b1r + ur,  b1i + ui);
  D = make_float2(b1r - ur,  b1i - ui);
}

// ---------------------------------------------------------------- radix-16 passes
__device__ __forceinline__ void fwd_pass16(float2* z, const float2* __restrict__ tw,
                                           int base, int jp, int st, int e) {
  float2 v[16]; int idx[16];
#pragma unroll
  for (int m = 0; m < 16; ++m) { idx[m] = LPZ(base + m * st); v[m] = z[idx[m]]; }
#pragma unroll
  for (int c = 0; c < 4; ++c) {
    const int jc = jp + c * st;
    dif4(v[c], v[c + 4], v[c + 8], v[c + 12],
         tw[jc << e], tw[(2 * jc) << e], tw[(3 * jc) << e]);
  }
  const float2 u1 = tw[jp << (e + 2)];
  const float2 u2 = tw[(2 * jp) << (e + 2)];
  const float2 u3 = tw[(3 * jp) << (e + 2)];
#pragma unroll
  for (int a = 0; a < 4; ++a)
    dif4(v[4 * a], v[4 * a + 1], v[4 * a + 2], v[4 * a + 3], u1, u2, u3);
#pragma unroll
  for (int m = 0; m < 16; ++m) z[idx[m]] = v[m];
}

__device__ __forceinline__ void inv_pass16(float2* z, const float2* __restrict__ tw,
                                           int base, int jp, int st, int e) {
  float2 v[16]; int idx[16];
#pragma unroll
  for (int m = 0; m < 16; ++m) { idx[m] = LPZ(base + m * st); v[m] = z[idx[m]]; }
  const float2 w1 = tw[jp << e];
  const float2 w2 = tw[(2 * jp) << e];
#pragma unroll
  for (int a = 0; a < 4; ++a)
    dit4(v[4 * a], v[4 * a + 1], v[4 * a + 2], v[4 * a + 3], w1, w2);
#pragma unroll
  for (int c = 0; c < 4; ++c) {
    const int jpp = c * st + jp;
    dit4(v[c], v[c + 4], v[c + 8], v[c + 12],
         tw[jpp << (e - 2)], tw[(2 * jpp) << (e - 2)]);
  }
#pragma unroll
  for (int m = 0; m < 16; ++m) z[idx[m]] = v[m];
}

// ---------------------------------------------------------------- forward 8192: 2 radix-16 + fused {5,3,1} tail
template <int NT>
__device__ __forceinline__ void fwd8192(float2* z, const float2* __restrict__ tw, int tid) {
  fwd_pass16(z, tw, tid, tid, 512, 0);
  __syncthreads();
  fwd_pass16(z, tw, ((tid >> 5) << 9) | (tid & 31), tid & 31, 32, 4);
  __syncthreads();
  if (tid < 256) {
    float2 v[32];
#pragma unroll
    for (int n = 0; n < 32; ++n) v[n] = z[LPZ(tid * 32 + n)];
#pragma unroll
    for (int p = 0; p < 8; ++p)
      dif4(v[p], v[p + 8], v[p + 16], v[p + 24],
           tw[p << 8], tw[(2 * p) << 8], tw[(3 * p) << 8]);
    const float2 one = make_float2(1.f, 0.f);
    const float2 o1 = tw[1 << 10], o2 = tw[2 << 10], o3 = tw[3 << 10];
#pragma unroll
    for (int a = 0; a < 4; ++a) {
      dif4(v[8 * a], v[8 * a + 2], v[8 * a + 4], v[8 * a + 6], one, one, one);
      dif4(v[8 * a + 1], v[8 * a + 3], v[8 * a + 5], v[8 * a + 7], o1, o2, o3);
    }
#pragma unroll
    for (int i = 0; i < 16; ++i) {
      const float2 U = v[2 * i], V = v[2 * i + 1];
      v[2 * i]     = make_float2(U.x + V.x, U.y + V.y);
      v[2 * i + 1] = make_float2(U.x - V.x, U.y - V.y);
    }
#pragma unroll
    for (int n = 0; n < 32; ++n) z[LPZ(tid * 32 + n)] = v[n];
  }
  __syncthreads();
}

// ---------------------------------------------------------------- inverse-core 4096: 3 radix-16
template <int NT>
__device__ __forceinline__ void inv4096(float2* z, const float2* __restrict__ tw, int tid) {
  if (tid < 256) inv_pass16(z, tw, tid << 4, 0, 1, 11);
  __syncthreads();
  if (tid < 256) inv_pass16(z, tw, ((tid >> 4) << 8) | (tid & 15), tid & 15, 16, 7);
  __syncthreads();
  if (tid < 256) inv_pass16(z, tw, tid, tid, 256, 3);
  __syncthreads();
}

// ---------------------------------------------------------------- paired h0 FFT
__global__ __launch_bounds__(512, 2) void fft_h0_pair(const float* __restrict__ h0T,
                                                      const float2* __restrict__ tw,
                                                      float2* __restrict__ h0f) {
  __shared__ float2 z[8192];
  const int d0 = blockIdx.x * 2, tid = threadIdx.x;
  const float* srcA = h0T + (size_t)d0 * 8192;
  const float* srcB = srcA + 8192;
  const int s0 = tid << 4;
#pragma unroll
  for (int m = 0; m < 16; ++m) z[LPZ(s0 + m)] = make_float2(srcA[s0 + m], srcB[s0 + m]);
  __syncthreads();
  fwd8192<512>(z, tw, tid);
  float2* H0 = h0f + (size_t)d0 * 4097;
  float2* H1 = H0 + 4097;
  for (int k = tid; k <= 4096; k += 512) {
    const float2 Zk = z[LPZ(BREV13(k))];
    const float2 Zm = z[LPZ(BREV13((8192 - k) & 8191))];
    H0[k] = make_float2(0.5f * (Zk.x + Zm.x), 0.5f * (Zk.y - Zm.y));
    H1[k] = make_float2(0.5f * (Zk.y + Zm.y), 0.5f * (Zm.x - Zk.x));
  }
}

// ---------------------------------------------------------------- fused per-(b,d) row pipeline
__global__ __launch_bounds__(512, 2) void fused_fft(u16* __restrict__ x3T,
                                                    const float2* __restrict__ tw,
                                                    const float2* __restrict__ h0f,
                                                    const float* __restrict__ w_short,
                                                    const float* __restrict__ b_short,
                                                    const float* __restrict__ w_cond1,
                                                    const float* __restrict__ b_cond1,
                                                    const float* __restrict__ w_cond2,
                                                    const float* __restrict__ b_cond2,
                                                    size_t bstr) {
  __shared__ float2 z[8192];
  const int d = blockIdx.x, tid = threadIdx.x;
  x3T += (size_t)blockIdx.y * bstr;
  u16* g0 = x3T + (size_t)d * 8192;
  const u16* g1 = x3T + (size_t)(768 + d) * 8192;
  const u16* g2 = x3T + (size_t)(1536 + d) * 8192;

  const float q0 = w_cond1[d * 3], q1 = w_cond1[d * 3 + 1], q2 = w_cond1[d * 3 + 2], bc1 = b_cond1[d];
  const float t00 = w_short[d * 3], t01 = w_short[d * 3 + 1], t02 = w_short[d * 3 + 2], bs0 = b_short[d];
  const float t10 = w_short[(768 + d) * 3], t11 = w_short[(768 + d) * 3 + 1], t12 = w_short[(768 + d) * 3 + 2], bs1 = b_short[768 + d];
  const float t20 = w_short[(1536 + d) * 3], t21 = w_short[(1536 + d) * 3 + 1], t22 = w_short[(1536 + d) * 3 + 2], bs2 = b_short[1536 + d];

  const int s0 = tid << 4;

  // conv phase (global -> regs -> z): z[s] = hc[s] + i*y[s]
  {
    const u16x8 ga0 = *(const u16x8*)&g0[s0];
    const u16x8 ga1 = *(const u16x8*)&g0[s0 + 8];
    const u16x8 gb0 = *(const u16x8*)&g2[s0];
    const u16x8 gb1 = *(const u16x8*)&g2[s0 + 8];
    float a[18], bz[18];
    a[0]  = s0 ? bf2f(g0[s0 - 1]) : 0.f;
    bz[0] = s0 ? bf2f(g2[s0 - 1]) : 0.f;
#pragma unroll
    for (int m = 0; m < 8; ++m) {
      a[1 + m] = bf2f(ga0[m]);  a[9 + m] = bf2f(ga1[m]);
      bz[1 + m] = bf2f(gb0[m]); bz[9 + m] = bf2f(gb1[m]);
    }
    a[17]  = (s0 + 16 < 8192) ? bf2f(g0[s0 + 16]) : 0.f;
    bz[17] = (s0 + 16 < 8192) ? bf2f(g2[s0 + 16]) : 0.f;
#pragma unroll
    for (int m = 0; m < 16; ++m) {
      const float s1v = t00 * a[m] + t01 * a[m + 1] + t02 * a[m + 2] + bs0;
      const float vvv = t20 * bz[m] + t21 * bz[m + 1] + t22 * bz[m + 2] + bs2;
      const float hcv = q0 * bz[m] + q1 * bz[m + 1] + q2 * bz[m + 2] + bc1;
      z[LPZ(s0 + m)] = make_float2(hcv, s1v * vvv);
    }
  }
  __syncthreads();

  fwd8192<512>(z, tw, tid);

  // mirror-paired unpack: thread covers k = kc and k = 4096-kc
  float hma[4], yra[4], yia[4];
  float hmb[4], yrb[4], yib[4];
  float hmc = 0.f, yrc = 0.f, yic = 0.f;
#pragma unroll
  for (int j = 0; j < 4; ++j) {
    const int kc = tid + j * 512;
    {
      const float2 Zk = z[LPZ(BREV13(kc))];
      const float2 Zm = z[LPZ(BREV13((8192 - kc) & 8191))];
      const float hcr = 0.5f * (Zk.x + Zm.x), hci = 0.5f * (Zk.y - Zm.y);
      hma[j] = sqrtf(hcr * hcr + hci * hci);
      yra[j] = 0.5f * (Zk.y + Zm.y);
      yia[j] = 0.5f * (Zm.x - Zk.x);
    }
    {
      const int k2 = 4096 - kc;
      const float2 Zk = z[LPZ(BREV13(k2))];
      const float2 Zm = z[LPZ(BREV13(4096 + kc))];
      const float hcr = 0.5f * (Zk.x + Zm.x), hci = 0.5f * (Zk.y - Zm.y);
      hmb[j] = sqrtf(hcr * hcr + hci * hci);
      yrb[j] = 0.5f * (Zk.y + Zm.y);
      yib[j] = 0.5f * (Zm.x - Zk.x);
    }
  }
  if (tid == 0) {
    const float2 Zk = z[LPZ(BREV13(2048))];
    const float2 Zm = z[LPZ(BREV13(6144))];
    const float hcr = 0.5f * (Zk.x + Zm.x), hci = 0.5f * (Zk.y - Zm.y);
    hmc = sqrtf(hcr * hcr + hci * hci);
    yrc = 0.5f * (Zk.y + Zm.y);
    yic = 0.5f * (Zm.x - Zk.x);
  }
  __syncthreads();
  float* hbuf = (float*)z;
#pragma unroll
  for (int j = 0; j < 4; ++j) {
    const int kc = tid + j * 512;
    hbuf[kc] = hma[j];
    hbuf[4096 - kc] = hmb[j];
  }
  if (tid == 0) hbuf[2048] = hmc;
  __syncthreads();

  // h_adapt + G (both mirrors) + pack -> Zc in regs (middle hm values from registers)
  const float c0 = w_cond2[d * 3], c1 = w_cond2[d * 3 + 1], c2 = w_cond2[d * 3 + 2], bb2 = b_cond2[d];
  const float2* H0 = h0f + (size_t)d * 4097;
  float zar[4], zai[4], zbr[4], zbi[4];
  float2 zc2048 = make_float2(0.f, 0.f);
#pragma unroll
  for (int j = 0; j < 4; ++j) {
    const int kc = tid + j * 512;
    const int k2 = 4096 - kc;
    const float aA = kc ? hbuf[kc - 1] : 0.f;
    const float zA = hbuf[kc + 1];
    const float haA = c0 * aA + c1 * hma[j] + c2 * zA + bb2;
    const float aB = hbuf[k2 - 1];
    const float zB = (k2 < 4096) ? hbuf[k2 + 1] : 0.f;
    const float haB = c0 * aB + c1 * hmb[j] + c2 * zB + bb2;
    const float2 hA = H0[kc];
    const float hrA = hA.x + haA, hiA = hA.y;
    float grA = yra[j] * hrA - yia[j] * hiA;
    float giA = yra[j] * hiA + yia[j] * hrA;
    if (kc == 0) giA = 0.f;
    const float2 hB = H0[k2];
    const float hrB = hB.x + haB, hiB = hB.y;
    float grB = yrb[j] * hrB - yib[j] * hiB;
    float giB = yrb[j] * hiB + yib[j] * hrB;
    if (k2 == 4096) giB = 0.f;
    const float Er = 0.5f * (grA + grB), Ei = 0.5f * (giA - giB);
    const float Pr = 0.5f * (grA - grB), Pi = 0.5f * (giA + giB);
    const float2 w = tw[kc];
    const float Or = Pr * w.x + Pi * w.y;
    const float Oi = Pi * w.x - Pr * w.y;
    zar[j] = Er - Oi; zai[j] = -(Ei + Or);
    zbr[j] = Er + Oi; zbi[j] = Ei - Or;
  }
  if (tid == 0) {
    const float aC = hbuf[2047], zC = hbuf[2049];
    const float haC = c0 * aC + c1 * hmc + c2 * zC + bb2;
    const float2 hC = H0[2048];
    const float hrC = hC.x + haC, hiC = hC.y;
    zc2048 = make_float2(yrc * hrC - yic * hiC, yrc * hiC + yic * hrC);
  }
  __syncthreads();
#pragma unroll
  for (int j = 0; j < 4; ++j) {
    const int kc = tid + j * 512;
    z[LPZ(BREV12(kc))] = make_float2(zar[j], zai[j]);
    if (kc) z[LPZ(BREV12(4096 - kc))] = make_float2(zbr[j], zbi[j]);
  }
  if (tid == 0) z[LPZ(BREV12(2048))] = zc2048;
  __syncthreads();

  // T14: issue g1 loads now; HBM latency hides under inv4096
  const u16x8 g1a = *(const u16x8*)&g1[s0];
  const u16x8 g1b = *(const u16x8*)&g1[s0 + 8];
  const float ge0 = s0 ? bf2f(g1[s0 - 1]) : 0.f;
  const float ge1 = (s0 + 16 < 8192) ? bf2f(g1[s0 + 16]) : 0.f;

  inv4096<512>(z, tw, tid);

  // final: y2 = irfft * conv3(g1,ws1) -> g0 (bf16)
  {
    float gg[18];
    gg[0] = ge0;
#pragma unroll
    for (int m = 0; m < 8; ++m) { gg[1 + m] = bf2f(g1a[m]); gg[9 + m] = bf2f(g1b[m]); }
    gg[17] = ge1;
    float2 zv[8];
#pragma unroll
    for (int r = 0; r < 8; ++r) zv[r] = z[LPZ((s0 >> 1) + r)];
    const float invM = 1.0f / 4096.0f;
    u16x8 o0, o1;
#pragma unroll
    for (int m = 0; m < 16; ++m) {
      const float xs = ((m & 1) ? -zv[m >> 1].y : zv[m >> 1].x) * invM;
      const float s2v = t10 * gg[m] + t11 * gg[m + 1] + t12 * gg[m + 2] + bs1;
      const u16 val = f2bf(xs * s2v);
      if (m < 8) o0[m] = val; else o1[m - 8] = val;
    }
    *(u16x8*)&g0[s0] = o0;
    *(u16x8*)&g0[s0 + 8] = o1;
  }
}

// ---------------------------------------------------------------- y2 transpose, vectorized u16x8 both sides
__global__ __launch_bounds__(256) void y2tv(const u16* __restrict__ Yr, u16* __restrict__ y2b,
                                            size_t in_str, size_t out_str) {
  __shared__ __align__(16) u16 T[4096];
  Yr  += (size_t)blockIdx.z * in_str;
  y2b += (size_t)blockIdx.z * out_str;
  const int d0 = blockIdx.x * 64, s0 = blockIdx.y * 64;
  const int t = threadIdx.x;
  const int r = t >> 2;
  const int c0 = t & 3;
#pragma unroll
  for (int h = 0; h < 2; ++h) {
    const int cc = c0 + h * 4;
    const u16x8 v = *(const u16x8*)&Yr[(size_t)(d0 + r) * 8192 + s0 + cc * 8];
#pragma unroll
    for (int q = 0; q < 8; ++q) {
      const int s = cc * 8 + q;
      T[s * 64 + (((r >> 3) ^ (s & 7)) << 3) + (r & 7)] = v[q];
    }
  }
  __syncthreads();
  const int l = t & 63, w = t >> 6;
#pragma unroll
  for (int h = 0; h < 2; ++h) {
    const int s = (w + h * 4) * 8 + (l >> 3);
    const int j = l & 7;
    const u16x8 o = *(const u16x8*)&T[s * 64 + ((j ^ (s & 7)) << 3)];
    *(u16x8*)&y2b[(size_t)(s0 + s) * 768 + d0 + j * 8] = o;
  }
}

// ---------------------------------------------------------------- launch
extern "C" void kernel_launch(void* const* d_in, const int* in_sizes, int n_in,
                              void* d_out, int out_size, void* d_ws, size_t ws_size,
                              hipStream_t stream) {
  (void)in_sizes; (void)n_in; (void)out_size;
  const float* x       = (const float*)d_in[0];
  const float* w_in    = (const float*)d_in[1];
  const float* b_in    = (const float*)d_in[2];
  const float* w_short = (const float*)d_in[3];
  const float* b_short = (const float*)d_in[4];
  const float* w_cond1 = (const float*)d_in[5];
  const float* b_cond1 = (const float*)d_in[6];
  const float* w_cond2 = (const float*)d_in[7];
  const float* b_cond2 = (const float*)d_in[8];
  const float* h0      = (const float*)d_in[9];
  const float* w_out   = (const float*)d_in[10];
  const float* b_out   = (const float*)d_in[11];

  float* ws = (float*)d_ws;
  float2* tw  = (float2*)ws;                      // [0, 16384)
  float2* h0f = (float2*)(ws + 16384);            // [16384, 6309376)
  const size_t BSTR = 18874368ull;                // u16 per x3T batch
  const size_t XSTR = 6291456ull;                 // u16 per x batch

  const bool t1 = ws_size >= 231282688ull;
  const bool t2 = !t1 && ws_size >= 193533952ull;

  if (t1) {
    u16* xb4    = (u16*)(ws + 6309376);
    u16* w_inb  = (u16*)(ws + 18892288);
    u16* w_outb = (u16*)(ws + 19777024);
    u16* x3Tb4  = (u16*)(ws + 20071936);
    float* h0T  = (float*)x3Tb4;                  // transient; consumed before gemm1 writes
    prologue_all<<<15008, 256, 0, stream>>>(x, w_in, w_out, h0, tw, h0T,
                                            w_inb, w_outb, xb4);
    fft_h0_pair<<<384, 512, 0, stream>>>(h0T, tw, h0f);
    gemm_bt<1><<<dim3(64, 18, 4), 256, 0, stream>>>(w_inb, xb4, b_in, x3Tb4,
                                                    8192, 768, 0, XSTR, BSTR);
    fused_fft<<<dim3(768, 4), 512, 0, stream>>>(x3Tb4, tw, h0f,
                                                w_short, b_short, w_cond1, b_cond1,
                                                w_cond2, b_cond2, BSTR);
    y2tv<<<dim3(12, 128, 4), 256, 0, stream>>>(x3Tb4, x3Tb4 + XSTR, BSTR, BSTR);
    gemm_bt<0><<<dim3(6, 64, 4), 256, 0, stream>>>(x3Tb4 + XSTR, w_outb, b_out,
                                                   (float*)d_out, 768, 768,
                                                   BSTR, 0, XSTR);
  } else if (t2) {
    u16* xb     = (u16*)(ws + 6309376);
    u16* w_inb  = (u16*)(ws + 9455104);
    u16* w_outb = (u16*)(ws + 10339840);
    u16* x3Tb   = (u16*)(ws + 10634752);
    float* h0T  = (float*)x3Tb;                   // transient; consumed before gemm1 writes
    twfill<<<32, 256, 0, stream>>>(tw);
    transp<<<dim3(12, 128), 256, 0, stream>>>(h0, h0T);
    fft_h0_pair<<<384, 512, 0, stream>>>(h0T, tw, h0f);
    cvt_bf16<<<864, 256, 0, stream>>>(w_in, w_inb, 221184);
    cvt_bf16<<<288, 256, 0, stream>>>(w_out, w_outb, 73728);
    for (int b = 0; b < 4; ++b) {
      cvt_bf16<<<3072, 256, 0, stream>>>(x + (size_t)b * XSTR, xb, 786432);
      gemm_bt<1><<<dim3(64, 18), 256, 0, stream>>>(w_inb, xb, b_in,
                                                   x3Tb + (size_t)b * BSTR, 8192, 768, 0, 0, 0);
    }
    fused_fft<<<dim3(768, 4), 512, 0, stream>>>(x3Tb, tw, h0f,
                                                w_short, b_short, w_cond1, b_cond1,
                                                w_cond2, b_cond2, BSTR);
    y2tv<<<dim3(12, 128, 4), 256, 0, stream>>>(x3Tb, x3Tb + XSTR, BSTR, BSTR);
    gemm_bt<0><<<dim3(6, 64, 4), 256, 0, stream>>>(x3Tb + XSTR, w_outb, b_out,
                                                   (float*)d_out, 768, 768,
                                                   BSTR, 0, XSTR);
  } else {
    u16* xb     = (u16*)(ws + 6309376);
    u16* w_inb  = (u16*)(ws + 9455104);
    u16* w_outb = (u16*)(ws + 10339840);
    u16* x3Tb   = (u16*)(ws + 10634752);
    float* h0T  = (float*)x3Tb;                   // transient; consumed before gemm1 writes
    twfill<<<32, 256, 0, stream>>>(tw);
    transp<<<dim3(12, 128), 256, 0, stream>>>(h0, h0T);
    fft_h0_pair<<<384, 512, 0, stream>>>(h0T, tw, h0f);
    cvt_bf16<<<864, 256, 0, stream>>>(w_in, w_inb, 221184);
    cvt_bf16<<<288, 256, 0, stream>>>(w_out, w_outb, 73728);
    for (int b = 0; b < 4; ++b) {
      cvt_bf16<<<3072, 256, 0, stream>>>(x + (size_t)b * XSTR, xb, 786432);
      gemm_bt<1><<<dim3(64, 18), 256, 0, stream>>>(w_inb, xb, b_in, x3Tb, 8192, 768, 0, 0, 0);
      fused_fft<<<dim3(768, 1), 512, 0, stream>>>(x3Tb, tw, h0f,
                                                  w_short, b_short, w_cond1, b_cond1,
                                                  w_cond2, b_cond2, 0);
      y2tv<<<dim3(12, 128, 1), 256, 0, stream>>>(x3Tb, x3Tb + XSTR, 0, 0);
      gemm_bt<0><<<dim3(6, 64, 1), 256, 0, stream>>>(x3Tb + XSTR, w_outb, b_out,
                                                     (float*)d_out + (size_t)b * XSTR,
                                                     768, 768, 0, 0, 0);
    }
  }
}

// Round 22
// 505.981 us; speedup vs baseline: 1.1009x; 1.0017x over previous
//
#include <hip/hip_runtime.h>
#include <math.h>

// B=4, S=8192, D=768, W=3D=2304
// Tiers by ws_size: T1 231.3MB | T2 193.5MB | T3 80.3MB.
// gemm_bt: BK=64 (8 glds16 + 2x16 MFMA per barrier pair) — halves barrier drains vs BK=32.

typedef unsigned short u16;
typedef short s16x8 __attribute__((ext_vector_type(8)));
typedef float f32x4 __attribute__((ext_vector_type(4)));
typedef u16 u16x8 __attribute__((ext_vector_type(8)));

#define LPZ(i) ((i) ^ (((i) >> 4) & 15) ^ (((i) >> 8) & 15))
#define BREV13(k) ((int)(__brev((unsigned)(k)) >> 19))
#define BREV12(k) ((int)(__brev((unsigned)(k)) >> 20))
#define CMUL(rr, ri, xr, xi, wr, wi) { rr = (xr)*(wr) - (xi)*(wi); ri = (xr)*(wi) + (xi)*(wr); }

__device__ __forceinline__ u16 f2bf(float f) {
  unsigned u = __float_as_uint(f);
  u = (u + 0x7FFFu + ((u >> 16) & 1u)) >> 16;
  return (u16)u;
}
__device__ __forceinline__ float bf2f(u16 u) { return __uint_as_float(((unsigned)u) << 16); }

__device__ __forceinline__ void glds16(const void* g, void* l) {
  __builtin_amdgcn_global_load_lds((const __attribute__((address_space(1))) unsigned*)g,
                                   (__attribute__((address_space(3))) unsigned*)l, 16, 0, 0);
}

__device__ __forceinline__ void cvt8(const float* __restrict__ in, u16* __restrict__ out, int i) {
  const float4 a = ((const float4*)in)[i * 2];
  const float4 b = ((const float4*)in)[i * 2 + 1];
  u16x8 r;
  r[0] = f2bf(a.x); r[1] = f2bf(a.y); r[2] = f2bf(a.z); r[3] = f2bf(a.w);
  r[4] = f2bf(b.x); r[5] = f2bf(b.y); r[6] = f2bf(b.z); r[7] = f2bf(b.w);
  ((u16x8*)out)[i] = r;
}

// ---------------------------------------------------------------- float -> bf16 (standalone, T2/T3)
__global__ __launch_bounds__(256) void cvt_bf16(const float* __restrict__ in,
                                                u16* __restrict__ out, int n8) {
  const int i = blockIdx.x * 256 + threadIdx.x;
  if (i < n8) cvt8(in, out, i);
}

// ---------------------------------------------------------------- twiddles (standalone, T2/T3)
__global__ void twfill(float2* __restrict__ tw) {
  const int k = blockIdx.x * 256 + threadIdx.x;
  if (k < 8192) {
    const double t = -2.0 * 3.14159265358979323846 * (double)k / 8192.0;
    tw[k] = make_float2((float)cos(t), (float)sin(t));
  }
}

// ---------------------------------------------------------------- h0 transpose body
__device__ __forceinline__ void transp_body(const float* __restrict__ in, float* __restrict__ out,
                                            int bx, int by, int tid) {
  __shared__ float T[64][65];
  const int d0 = bx * 64, s0 = by * 64;
  const int c = tid & 63, r0 = tid >> 6;
#pragma unroll
  for (int i = 0; i < 16; ++i) {
    const int r = r0 + i * 4;
    T[r][c] = in[(size_t)(s0 + r) * 768 + d0 + c];
  }
  __syncthreads();
#pragma unroll
  for (int i = 0; i < 16; ++i) {
    const int r = r0 + i * 4;
    out[(size_t)(d0 + r) * 8192 + s0 + c] = T[c][r];
  }
}

__global__ __launch_bounds__(256) void transp(const float* __restrict__ in, float* __restrict__ out) {
  transp_body(in, out, blockIdx.x, blockIdx.y, threadIdx.x);
}

// ---------------------------------------------------------------- merged prologue (T1)
__global__ __launch_bounds__(256) void prologue_all(const float* __restrict__ x,
                                                    const float* __restrict__ w_in,
                                                    const float* __restrict__ w_out,
                                                    const float* __restrict__ h0,
                                                    float2* __restrict__ tw,
                                                    float* __restrict__ h0T,
                                                    u16* __restrict__ w_inb,
                                                    u16* __restrict__ w_outb,
                                                    u16* __restrict__ xb4) {
  const int b = blockIdx.x, tid = threadIdx.x;
  if (b < 12288) {
    cvt8(x, xb4, b * 256 + tid);
  } else if (b < 13152) {
    const int i = (b - 12288) * 256 + tid;
    if (i < 221184) cvt8(w_in, w_inb, i);
  } else if (b < 13440) {
    const int i = (b - 13152) * 256 + tid;
    if (i < 73728) cvt8(w_out, w_outb, i);
  } else if (b < 14976) {
    const int idx = b - 13440;
    transp_body(h0, h0T, idx % 12, idx / 12, tid);
  } else {
    const int k = (b - 14976) * 256 + tid;
    if (k < 8192) {
      const double t = -2.0 * 3.14159265358979323846 * (double)k / 8192.0;
      tw[k] = make_float2((float)cos(t), (float)sin(t));
    }
  }
}

// ---------------------------------------------------------------- MFMA GEMM, BK=64
template <int BIAS_M>
__global__ __launch_bounds__(256) void gemm_bt(const u16* __restrict__ A,
                                               const u16* __restrict__ B,
                                               const float* __restrict__ bias,
                                               void* __restrict__ Cout,
                                               int N, int K,
                                               size_t As_str, size_t Bs_str, size_t Cs_str) {
  __shared__ __align__(16) u16 As[8192];
  __shared__ __align__(16) u16 Bs[8192];
  A += (size_t)blockIdx.z * As_str;
  B += (size_t)blockIdx.z * Bs_str;
  const int tid = threadIdx.x;
  const int w = tid >> 6, l = tid & 63;
  const int m0 = blockIdx.y * 128, n0 = blockIdx.x * 128;
  const int wr = w >> 1, wc = w & 1;
  const int lr = l & 15, kc = l >> 4;

  const int p0 = w * 64 + l;
  const int p1 = p0 + 256;
  const int sl0 = (p0 & 7) ^ ((p0 >> 3) & 7);
  const int sl1 = (p1 & 7) ^ ((p1 >> 3) & 7);
  const int r0 = ((p0 >> 3) << 1) | (sl0 >> 2), ka = (sl0 & 3) << 3;
  const int r1 = ((p1 >> 3) << 1) | (sl1 >> 2), kb = (sl1 & 3) << 3;
  const u16* gA0 = A + (size_t)(m0 + r0) * K + ka;
  const u16* gA1 = A + (size_t)(m0 + r1) * K + kb;
  const u16* gB0 = B + (size_t)(n0 + r0) * K + ka;
  const u16* gB1 = B + (size_t)(n0 + r1) * K + kb;
  u16* lA0 = &As[(size_t)w * 512];
  u16* lA1 = &As[(size_t)(4 + w) * 512];
  u16* lB0 = &Bs[(size_t)w * 512];
  u16* lB1 = &Bs[(size_t)(4 + w) * 512];

  f32x4 acc[4][4] = {};

  for (int k0 = 0; k0 < K; k0 += 64) {
    glds16(gA0 + k0, lA0);
    glds16(gA1 + k0, lA1);
    glds16(gB0 + k0, lB0);
    glds16(gB1 + k0, lB1);
    glds16(gA0 + k0 + 32, lA0 + 4096);
    glds16(gA1 + k0 + 32, lA1 + 4096);
    glds16(gB0 + k0 + 32, lB0 + 4096);
    glds16(gB1 + k0 + 32, lB1 + 4096);
    __syncthreads();
#pragma unroll
    for (int h = 0; h < 2; ++h) {
      const int off = h * 4096;
      s16x8 af[4], bfr[4];
#pragma unroll
      for (int mi = 0; mi < 4; ++mi) {
        const int row = wr * 64 + mi * 16 + lr;
        const int slot = (((lr & 1) << 2) | kc) ^ ((lr >> 1) & 7);
        af[mi] = *(const s16x8*)&As[off + (row >> 1) * 64 + slot * 8];
      }
#pragma unroll
      for (int ni = 0; ni < 4; ++ni) {
        const int row = wc * 64 + ni * 16 + lr;
        const int slot = (((lr & 1) << 2) | kc) ^ ((lr >> 1) & 7);
        bfr[ni] = *(const s16x8*)&Bs[off + (row >> 1) * 64 + slot * 8];
      }
#pragma unroll
      for (int mi = 0; mi < 4; ++mi)
#pragma unroll
        for (int ni = 0; ni < 4; ++ni)
          acc[mi][ni] = __builtin_amdgcn_mfma_f32_16x16x32_bf16(af[mi], bfr[ni], acc[mi][ni], 0, 0, 0);
    }
    __syncthreads();
  }

  const int rbase = m0 + wr * 64 + (kc << 2);
  const int cbase = n0 + wc * 64 + lr;
#pragma unroll
  for (int mi = 0; mi < 4; ++mi)
#pragma unroll
    for (int j = 0; j < 4; ++j) {
      const int row = rbase + mi * 16 + j;
      const float bm = BIAS_M ? bias[row] : 0.f;
#pragma unroll
      for (int ni = 0; ni < 4; ++ni) {
        const int col = cbase + ni * 16;
        const float v = acc[mi][ni][j] + (BIAS_M ? bm : bias[col]);
        if (BIAS_M) ((u16*)Cout)[(size_t)blockIdx.z * Cs_str + (size_t)row * N + col] = f2bf(v);
        else ((float*)Cout)[(size_t)blockIdx.z * Cs_str + (size_t)row * N + col] = v;
      }
    }
}

// ---------------------------------------------------------------- butterfly bodies
__device__ __forceinline__ void dif4(float2& A, float2& B, float2& C, float2& D,
                                     float2 w1, float2 w2, float2 w3) {
  const float apr = A.x + C.x, api = A.y + C.y, amr = A.x - C.x, ami = A.y - C.y;
  const float bpr = B.x + D.x, bpi = B.y + D.y, bmr = B.x - D.x, bmi = B.y - D.y;
  const float2 o0 = make_float2(apr + bpr, api + bpi);
  const float x1r = apr - bpr, x1i = api - bpi;
  float2 o1; CMUL(o1.x, o1.y, x1r, x1i, w2.x, w2.y);
  const float x2r = amr + bmi, x2i = ami - bmr;
  float2 o2; CMUL(o2.x, o2.y, x2r, x2i, w1.x, w1.y);
  const float x3r = amr - bmi, x3i = ami + bmr;
  float2 o3; CMUL(o3.x, o3.y, x3r, x3i, w3.x, w3.y);
  A = o0; B = o1; C = o2; D = o3;
}

__device__ __forceinline__ void dit4(float2& A, float2& B, float2& C, float2& D,
                                     float2 w1, float2 w2) {
  float vbr, vbi, vdr, vdi;
  CMUL(vbr, vbi, B.x, B.y, w2.x, w2.y);
  CMUL(vdr, vdi, D.x, D.y, w2.x, w2.y);
  const float a1r = A.x + vbr, a1i = A.y + vbi;
  const float b1r = A.x - vbr, b1i = A.y - vbi;
  const float c1r = C.x + vdr, c1i = C.y + vdi;
  const float d1r = C.x - vdr, d1i = C.y - vdi;
  float t1r, t1i, ur, ui;
  CMUL(t1r, t1i, c1r, c1i, w1.x, w1.y);
  CMUL(ur, ui, d1r, d1i, w1.y, -w1.x);
  A = make_float2(a1r + t1r, a1i + t1i);
  C = make_float2(a1r - t1r, a1i - t1i);
  B = make_float2(b1r + ur,  b1i + ui);
  D = make_float2(b1r - ur,  b1i - ui);
}

// ---------------------------------------------------------------- radix-16 passes
__device__ __forceinline__ void fwd_pass16(float2* z, const float2* __restrict__ tw,
                                           int base, int jp, int st, int e) {
  float2 v[16]; int idx[16];
#pragma unroll
  for (int m = 0; m < 16; ++m) { idx[m] = LPZ(base + m * st); v[m] = z[idx[m]]; }
#pragma unroll
  for (int c = 0; c < 4; ++c) {
    const int jc = jp + c * st;
    dif4(v[c], v[c + 4], v[c + 8], v[c + 12],
         tw[jc << e], tw[(2 * jc) << e], tw[(3 * jc) << e]);
  }
  const float2 u1 = tw[jp << (e + 2)];
  const float2 u2 = tw[(2 * jp) << (e + 2)];
  const float2 u3 = tw[(3 * jp) << (e + 2)];
#pragma unroll
  for (int a = 0; a < 4; ++a)
    dif4(v[4 * a], v[4 * a + 1], v[4 * a + 2], v[4 * a + 3], u1, u2, u3);
#pragma unroll
  for (int m = 0; m < 16; ++m) z[idx[m]] = v[m];
}

__device__ __forceinline__ void inv_pass16(float2* z, const float2* __restrict__ tw,
                                           int base, int jp, int st, int e) {
  float2 v[16]; int idx[16];
#pragma unroll
  for (int m = 0; m < 16; ++m) { idx[m] = LPZ(base + m * st); v[m] = z[idx[m]]; }
  const float2 w1 = tw[jp << e];
  const float2 w2 = tw[(2 * jp) << e];
#pragma unroll
  for (int a = 0; a < 4; ++a)
    dit4(v[4 * a], v[4 * a + 1], v[4 * a + 2], v[4 * a + 3], w1, w2);
#pragma unroll
  for (int c = 0; c < 4; ++c) {
    const int jpp = c * st + jp;
    dit4(v[c], v[c + 4], v[c + 8], v[c + 12],
         tw[jpp << (e - 2)], tw[(2 * jpp) << (e - 2)]);
  }
#pragma unroll
  for (int m = 0; m < 16; ++m) z[idx[m]] = v[m];
}

// ---------------------------------------------------------------- forward 8192: 2 radix-16 + fused {5,3,1} tail
template <int NT>
__device__ __forceinline__ void fwd8192(float2* z, const float2* __restrict__ tw, int tid) {
  fwd_pass16(z, tw, tid, tid, 512, 0);
  __syncthreads();
  fwd_pass16(z, tw, ((tid >> 5) << 9) | (tid & 31), tid & 31, 32, 4);
  __syncthreads();
  if (tid < 256) {
    float2 v[32];
#pragma unroll
    for (int n = 0; n < 32; ++n) v[n] = z[LPZ(tid * 32 + n)];
#pragma unroll
    for (int p = 0; p < 8; ++p)
      dif4(v[p], v[p + 8], v[p + 16], v[p + 24],
           tw[p << 8], tw[(2 * p) << 8], tw[(3 * p) << 8]);
    const float2 one = make_float2(1.f, 0.f);
    const float2 o1 = tw[1 << 10], o2 = tw[2 << 10], o3 = tw[3 << 10];
#pragma unroll
    for (int a = 0; a < 4; ++a) {
      dif4(v[8 * a], v[8 * a + 2], v[8 * a + 4], v[8 * a + 6], one, one, one);
      dif4(v[8 * a + 1], v[8 * a + 3], v[8 * a + 5], v[8 * a + 7], o1, o2, o3);
    }
#pragma unroll
    for (int i = 0; i < 16; ++i) {
      const float2 U = v[2 * i], V = v[2 * i + 1];
      v[2 * i]     = make_float2(U.x + V.x, U.y + V.y);
      v[2 * i + 1] = make_float2(U.x - V.x, U.y - V.y);
    }
#pragma unroll
    for (int n = 0; n < 32; ++n) z[LPZ(tid * 32 + n)] = v[n];
  }
  __syncthreads();
}

// ---------------------------------------------------------------- inverse-core 4096: 3 radix-16
template <int NT>
__device__ __forceinline__ void inv4096(float2* z, const float2* __restrict__ tw, int tid) {
  if (tid < 256) inv_pass16(z, tw, tid << 4, 0, 1, 11);
  __syncthreads();
  if (tid < 256) inv_pass16(z, tw, ((tid >> 4) << 8) | (tid & 15), tid & 15, 16, 7);
  __syncthreads();
  if (tid < 256) inv_pass16(z, tw, tid, tid, 256, 3);
  __syncthreads();
}

// ---------------------------------------------------------------- paired h0 FFT
__global__ __launch_bounds__(512, 2) void fft_h0_pair(const float* __restrict__ h0T,
                                                      const float2* __restrict__ tw,
                                                      float2* __restrict__ h0f) {
  __shared__ float2 z[8192];
  const int d0 = blockIdx.x * 2, tid = threadIdx.x;
  const float* srcA = h0T + (size_t)d0 * 8192;
  const float* srcB = srcA + 8192;
  const int s0 = tid << 4;
#pragma unroll
  for (int m = 0; m < 16; ++m) z[LPZ(s0 + m)] = make_float2(srcA[s0 + m], srcB[s0 + m]);
  __syncthreads();
  fwd8192<512>(z, tw, tid);
  float2* H0 = h0f + (size_t)d0 * 4097;
  float2* H1 = H0 + 4097;
  for (int k = tid; k <= 4096; k += 512) {
    const float2 Zk = z[LPZ(BREV13(k))];
    const float2 Zm = z[LPZ(BREV13((8192 - k) & 8191))];
    H0[k] = make_float2(0.5f * (Zk.x + Zm.x), 0.5f * (Zk.y - Zm.y));
    H1[k] = make_float2(0.5f * (Zk.y + Zm.y), 0.5f * (Zm.x - Zk.x));
  }
}

// ---------------------------------------------------------------- fused per-(b,d) row pipeline
__global__ __launch_bounds__(512, 2) void fused_fft(u16* __restrict__ x3T,
                                                    const float2* __restrict__ tw,
                                                    const float2* __restrict__ h0f,
                                                    const float* __restrict__ w_short,
                                                    const float* __restrict__ b_short,
                                                    const float* __restrict__ w_cond1,
                                                    const float* __restrict__ b_cond1,
                                                    const float* __restrict__ w_cond2,
                                                    const float* __restrict__ b_cond2,
                                                    size_t bstr) {
  __shared__ float2 z[8192];
  const int d = blockIdx.x, tid = threadIdx.x;
  x3T += (size_t)blockIdx.y * bstr;
  u16* g0 = x3T + (size_t)d * 8192;
  const u16* g1 = x3T + (size_t)(768 + d) * 8192;
  const u16* g2 = x3T + (size_t)(1536 + d) * 8192;

  const float q0 = w_cond1[d * 3], q1 = w_cond1[d * 3 + 1], q2 = w_cond1[d * 3 + 2], bc1 = b_cond1[d];
  const float t00 = w_short[d * 3], t01 = w_short[d * 3 + 1], t02 = w_short[d * 3 + 2], bs0 = b_short[d];
  const float t10 = w_short[(768 + d) * 3], t11 = w_short[(768 + d) * 3 + 1], t12 = w_short[(768 + d) * 3 + 2], bs1 = b_short[768 + d];
  const float t20 = w_short[(1536 + d) * 3], t21 = w_short[(1536 + d) * 3 + 1], t22 = w_short[(1536 + d) * 3 + 2], bs2 = b_short[1536 + d];

  const int s0 = tid << 4;

  // conv phase (global -> regs -> z): z[s] = hc[s] + i*y[s]
  {
    const u16x8 ga0 = *(const u16x8*)&g0[s0];
    const u16x8 ga1 = *(const u16x8*)&g0[s0 + 8];
    const u16x8 gb0 = *(const u16x8*)&g2[s0];
    const u16x8 gb1 = *(const u16x8*)&g2[s0 + 8];
    float a[18], bz[18];
    a[0]  = s0 ? bf2f(g0[s0 - 1]) : 0.f;
    bz[0] = s0 ? bf2f(g2[s0 - 1]) : 0.f;
#pragma unroll
    for (int m = 0; m < 8; ++m) {
      a[1 + m] = bf2f(ga0[m]);  a[9 + m] = bf2f(ga1[m]);
      bz[1 + m] = bf2f(gb0[m]); bz[9 + m] = bf2f(gb1[m]);
    }
    a[17]  = (s0 + 16 < 8192) ? bf2f(g0[s0 + 16]) : 0.f;
    bz[17] = (s0 + 16 < 8192) ? bf2f(g2[s0 + 16]) : 0.f;
#pragma unroll
    for (int m = 0; m < 16; ++m) {
      const float s1v = t00 * a[m] + t01 * a[m + 1] + t02 * a[m + 2] + bs0;
      const float vvv = t20 * bz[m] + t21 * bz[m + 1] + t22 * bz[m + 2] + bs2;
      const float hcv = q0 * bz[m] + q1 * bz[m + 1] + q2 * bz[m + 2] + bc1;
      z[LPZ(s0 + m)] = make_float2(hcv, s1v * vvv);
    }
  }
  __syncthreads();

  fwd8192<512>(z, tw, tid);

  // mirror-paired unpack: thread covers k = kc and k = 4096-kc
  float hma[4], yra[4], yia[4];
  float hmb[4], yrb[4], yib[4];
  float hmc = 0.f, yrc = 0.f, yic = 0.f;
#pragma unroll
  for (int j = 0; j < 4; ++j) {
    const int kc = tid + j * 512;
    {
      const float2 Zk = z[LPZ(BREV13(kc))];
      const float2 Zm = z[LPZ(BREV13((8192 - kc) & 8191))];
      const float hcr = 0.5f * (Zk.x + Zm.x), hci = 0.5f * (Zk.y - Zm.y);
      hma[j] = sqrtf(hcr * hcr + hci * hci);
      yra[j] = 0.5f * (Zk.y + Zm.y);
      yia[j] = 0.5f * (Zm.x - Zk.x);
    }
    {
      const int k2 = 4096 - kc;
      const float2 Zk = z[LPZ(BREV13(k2))];
      const float2 Zm = z[LPZ(BREV13(4096 + kc))];
      const float hcr = 0.5f * (Zk.x + Zm.x), hci = 0.5f * (Zk.y - Zm.y);
      hmb[j] = sqrtf(hcr * hcr + hci * hci);
      yrb[j] = 0.5f * (Zk.y + Zm.y);
      yib[j] = 0.5f * (Zm.x - Zk.x);
    }
  }
  if (tid == 0) {
    const float2 Zk = z[LPZ(BREV13(2048))];
    const float2 Zm = z[LPZ(BREV13(6144))];
    const float hcr = 0.5f * (Zk.x + Zm.x), hci = 0.5f * (Zk.y - Zm.y);
    hmc = sqrtf(hcr * hcr + hci * hci);
    yrc = 0.5f * (Zk.y + Zm.y);
    yic = 0.5f * (Zm.x - Zk.x);
  }
  __syncthreads();
  float* hbuf = (float*)z;
#pragma unroll
  for (int j = 0; j < 4; ++j) {
    const int kc = tid + j * 512;
    hbuf[kc] = hma[j];
    hbuf[4096 - kc] = hmb[j];
  }
  if (tid == 0) hbuf[2048] = hmc;
  __syncthreads();

  // h_adapt + G (both mirrors) + pack -> Zc in regs
  const float c0 = w_cond2[d * 3], c1 = w_cond2[d * 3 + 1], c2 = w_cond2[d * 3 + 2], bb2 = b_cond2[d];
  const float2* H0 = h0f + (size_t)d * 4097;
  float zar[4], zai[4], zbr[4], zbi[4];
  float2 zc2048 = make_float2(0.f, 0.f);
#pragma unroll
  for (int j = 0; j < 4; ++j) {
    const int kc = tid + j * 512;
    const int k2 = 4096 - kc;
    const float aA = kc ? hbuf[kc - 1] : 0.f;
    const float zA = hbuf[kc + 1];
    const float haA = c0 * aA + c1 * hma[j] + c2 * zA + bb2;
    const float aB = hbuf[k2 - 1];
    const float zB = (k2 < 4096) ? hbuf[k2 + 1] : 0.f;
    const float haB = c0 * aB + c1 * hmb[j] + c2 * zB + bb2;
    const float2 hA = H0[kc];
    const float hrA = hA.x + haA, hiA = hA.y;
    float grA = yra[j] * hrA - yia[j] * hiA;
    float giA = yra[j] * hiA + yia[j] * hrA;
    if (kc == 0) giA = 0.f;
    const float2 hB = H0[k2];
    const float hrB = hB.x + haB, hiB = hB.y;
    float grB = yrb[j] * hrB - yib[j] * hiB;
    float giB = yrb[j] * hiB + yib[j] * hrB;
    if (k2 == 4096) giB = 0.f;
    const float Er = 0.5f * (grA + grB), Ei = 0.5f * (giA - giB);
    const float Pr = 0.5f * (grA - grB), Pi = 0.5f * (giA + giB);
    const float2 w = tw[kc];
    const float Or = Pr * w.x + Pi * w.y;
    const float Oi = Pi * w.x - Pr * w.y;
    zar[j] = Er - Oi; zai[j] = -(Ei + Or);
    zbr[j] = Er + Oi; zbi[j] = Ei - Or;
  }
  if (tid == 0) {
    const float aC = hbuf[2047], zC = hbuf[2049];
    const float haC = c0 * aC + c1 * hmc + c2 * zC + bb2;
    const float2 hC = H0[2048];
    const float hrC = hC.x + haC, hiC = hC.y;
    zc2048 = make_float2(yrc * hrC - yic * hiC, yrc * hiC + yic * hrC);
  }
  __syncthreads();
#pragma unroll
  for (int j = 0; j < 4; ++j) {
    const int kc = tid + j * 512;
    z[LPZ(BREV12(kc))] = make_float2(zar[j], zai[j]);
    if (kc) z[LPZ(BREV12(4096 - kc))] = make_float2(zbr[j], zbi[j]);
  }
  if (tid == 0) z[LPZ(BREV12(2048))] = zc2048;
  __syncthreads();

  // T14: issue g1 loads now; HBM latency hides under inv4096
  const u16x8 g1a = *(const u16x8*)&g1[s0];
  const u16x8 g1b = *(const u16x8*)&g1[s0 + 8];
  const float ge0 = s0 ? bf2f(g1[s0 - 1]) : 0.f;
  const float ge1 = (s0 + 16 < 8192) ? bf2f(g1[s0 + 16]) : 0.f;

  inv4096<512>(z, tw, tid);

  // final: y2 = irfft * conv3(g1,ws1) -> g0 (bf16)
  {
    float gg[18];
    gg[0] = ge0;
#pragma unroll
    for (int m = 0; m < 8; ++m) { gg[1 + m] = bf2f(g1a[m]); gg[9 + m] = bf2f(g1b[m]); }
    gg[17] = ge1;
    float2 zv[8];
#pragma unroll
    for (int r = 0; r < 8; ++r) zv[r] = z[LPZ((s0 >> 1) + r)];
    const float invM = 1.0f / 4096.0f;
    u16x8 o0, o1;
#pragma unroll
    for (int m = 0; m < 16; ++m) {
      const float xs = ((m & 1) ? -zv[m >> 1].y : zv[m >> 1].x) * invM;
      const float s2v = t10 * gg[m] + t11 * gg[m + 1] + t12 * gg[m + 2] + bs1;
      const u16 val = f2bf(xs * s2v);
      if (m < 8) o0[m] = val; else o1[m - 8] = val;
    }
    *(u16x8*)&g0[s0] = o0;
    *(u16x8*)&g0[s0 + 8] = o1;
  }
}

// ---------------------------------------------------------------- y2 transpose, vectorized u16x8 both sides
__global__ __launch_bounds__(256) void y2tv(const u16* __restrict__ Yr, u16* __restrict__ y2b,
                                            size_t in_str, size_t out_str) {
  __shared__ __align__(16) u16 T[4096];
  Yr  += (size_t)blockIdx.z * in_str;
  y2b += (size_t)blockIdx.z * out_str;
  const int d0 = blockIdx.x * 64, s0 = blockIdx.y * 64;
  const int t = threadIdx.x;
  const int r = t >> 2;
  const int c0 = t & 3;
#pragma unroll
  for (int h = 0; h < 2; ++h) {
    const int cc = c0 + h * 4;
    const u16x8 v = *(const u16x8*)&Yr[(size_t)(d0 + r) * 8192 + s0 + cc * 8];
#pragma unroll
    for (int q = 0; q < 8; ++q) {
      const int s = cc * 8 + q;
      T[s * 64 + (((r >> 3) ^ (s & 7)) << 3) + (r & 7)] = v[q];
    }
  }
  __syncthreads();
  const int l = t & 63, w = t >> 6;
#pragma unroll
  for (int h = 0; h < 2; ++h) {
    const int s = (w + h * 4) * 8 + (l >> 3);
    const int j = l & 7;
    const u16x8 o = *(const u16x8*)&T[s * 64 + ((j ^ (s & 7)) << 3)];
    *(u16x8*)&y2b[(size_t)(s0 + s) * 768 + d0 + j * 8] = o;
  }
}

// ---------------------------------------------------------------- launch
extern "C" void kernel_launch(void* const* d_in, const int* in_sizes, int n_in,
                              void* d_out, int out_size, void* d_ws, size_t ws_size,
                              hipStream_t stream) {
  (void)in_sizes; (void)n_in; (void)out_size;
  const float* x       = (const float*)d_in[0];
  const float* w_in    = (const float*)d_in[1];
  const float* b_in    = (const float*)d_in[2];
  const float* w_short = (const float*)d_in[3];
  const float* b_short = (const float*)d_in[4];
  const float* w_cond1 = (const float*)d_in[5];
  const float* b_cond1 = (const float*)d_in[6];
  const float* w_cond2 = (const float*)d_in[7];
  const float* b_cond2 = (const float*)d_in[8];
  const float* h0      = (const float*)d_in[9];
  const float* w_out   = (const float*)d_in[10];
  const float* b_out   = (const float*)d_in[11];

  float* ws = (float*)d_ws;
  float2* tw  = (float2*)ws;                      // [0, 16384)
  float2* h0f = (float2*)(ws + 16384);            // [16384, 6309376)
  const size_t BSTR = 18874368ull;                // u16 per x3T batch
  const size_t XSTR = 6291456ull;                 // u16 per x batch

  const bool t1 = ws_size >= 231282688ull;
  const bool t2 = !t1 && ws_size >= 193533952ull;

  if (t1) {
    u16* xb4    = (u16*)(ws + 6309376);
    u16* w_inb  = (u16*)(ws + 18892288);
    u16* w_outb = (u16*)(ws + 19777024);
    u16* x3Tb4  = (u16*)(ws + 20071936);
    float* h0T  = (float*)x3Tb4;                  // transient; consumed before gemm1 writes
    prologue_all<<<15008, 256, 0, stream>>>(x, w_in, w_out, h0, tw, h0T,
                                            w_inb, w_outb, xb4);
    fft_h0_pair<<<384, 512, 0, stream>>>(h0T, tw, h0f);
    gemm_bt<1><<<dim3(64, 18, 4), 256, 0, stream>>>(w_inb, xb4, b_in, x3Tb4,
                                                    8192, 768, 0, XSTR, BSTR);
    fused_fft<<<dim3(768, 4), 512, 0, stream>>>(x3Tb4, tw, h0f,
                                                w_short, b_short, w_cond1, b_cond1,
                                                w_cond2, b_cond2, BSTR);
    y2tv<<<dim3(12, 128, 4), 256, 0, stream>>>(x3Tb4, x3Tb4 + XSTR, BSTR, BSTR);
    gemm_bt<0><<<dim3(6, 64, 4), 256, 0, stream>>>(x3Tb4 + XSTR, w_outb, b_out,
                                                   (float*)d_out, 768, 768,
                                                   BSTR, 0, XSTR);
  } else if (t2) {
    u16* xb     = (u16*)(ws + 6309376);
    u16* w_inb  = (u16*)(ws + 9455104);
    u16* w_outb = (u16*)(ws + 10339840);
    u16* x3Tb   = (u16*)(ws + 10634752);
    float* h0T  = (float*)x3Tb;                   // transient; consumed before gemm1 writes
    twfill<<<32, 256, 0, stream>>>(tw);
    transp<<<dim3(12, 128), 256, 0, stream>>>(h0, h0T);
    fft_h0_pair<<<384, 512, 0, stream>>>(h0T, tw, h0f);
    cvt_bf16<<<864, 256, 0, stream>>>(w_in, w_inb, 221184);
    cvt_bf16<<<288, 256, 0, stream>>>(w_out, w_outb, 73728);
    for (int b = 0; b < 4; ++b) {
      cvt_bf16<<<3072, 256, 0, stream>>>(x + (size_t)b * XSTR, xb, 786432);
      gemm_bt<1><<<dim3(64, 18), 256, 0, stream>>>(w_inb, xb, b_in,
                                                   x3Tb + (size_t)b * BSTR, 8192, 768, 0, 0, 0);
    }
    fused_fft<<<dim3(768, 4), 512, 0, stream>>>(x3Tb, tw, h0f,
                                                w_short, b_short, w_cond1, b_cond1,
                                                w_cond2, b_cond2, BSTR);
    y2tv<<<dim3(12, 128, 4), 256, 0, stream>>>(x3Tb, x3Tb + XSTR, BSTR, BSTR);
    gemm_bt<0><<<dim3(6, 64, 4), 256, 0, stream>>>(x3Tb + XSTR, w_outb, b_out,
                                                   (float*)d_out, 768, 768,
                                                   BSTR, 0, XSTR);
  } else {
    u16* xb     = (u16*)(ws + 6309376);
    u16* w_inb  = (u16*)(ws + 9455104);
    u16* w_outb = (u16*)(ws + 10339840);
    u16* x3Tb   = (u16*)(ws + 10634752);
    float* h0T  = (float*)x3Tb;                   // transient; consumed before gemm1 writes
    twfill<<<32, 256, 0, stream>>>(tw);
    transp<<<dim3(12, 128), 256, 0, stream>>>(h0, h0T);
    fft_h0_pair<<<384, 512, 0, stream>>>(h0T, tw, h0f);
    cvt_bf16<<<864, 256, 0, stream>>>(w_in, w_inb, 221184);
    cvt_bf16<<<288, 256, 0, stream>>>(w_out, w_outb, 73728);
    for (int b = 0; b < 4; ++b) {
      cvt_bf16<<<3072, 256, 0, stream>>>(x + (size_t)b * XSTR, xb, 786432);
      gemm_bt<1><<<dim3(64, 18), 256, 0, stream>>>(w_inb, xb, b_in, x3Tb, 8192, 768, 0, 0, 0);
      fused_fft<<<dim3(768, 1), 512, 0, stream>>>(x3Tb, tw, h0f,
                                                  w_short, b_short, w_cond1, b_cond1,
                                                  w_cond2, b_cond2, 0);
      y2tv<<<dim3(12, 128, 1), 256, 0, stream>>>(x3Tb, x3Tb + XSTR, 0, 0);
      gemm_bt<0><<<dim3(6, 64, 1), 256, 0, stream>>>(x3Tb + XSTR, w_outb, b_out,
                                                     (float*)d_out + (size_t)b * XSTR,
                                                     768, 768, 0, 0, 0);
    }
  }
}